// Round 11
// baseline (1559.569 us; speedup 1.0000x reference)
//
#include <hip/hip_runtime.h>
#include <hip/hip_bf16.h>
#include <hip/hip_fp16.h>

typedef _Float16 f16;
typedef _Float16 half8 __attribute__((ext_vector_type(8)));
typedef _Float16 half4 __attribute__((ext_vector_type(4)));
typedef float   floatx4 __attribute__((ext_vector_type(4)));

#define N_TOK   8192
#define D_DIM   1024
#define E_NUM   8
#define DF_DIM  4096
#define MAX_SLOTS 17408   // 16384 + 8*128 padding
#define MAX_RT    136     // MAX_SLOTS / 128

// meta layout (int32 indices)
#define MI_COUNT  0    // [8]
#define MI_CURSOR 8    // [8]
#define MI_OFF    16   // [9]
#define MI_TOTAL  25   // [1]  (# of 128-row tiles)
#define MI_RTE    26   // [136]
#define MI_SUMG   168  // [8] floats

__device__ __forceinline__ void gld_lds16(const void* g, void* l) {
    __builtin_amdgcn_global_load_lds(
        (__attribute__((address_space(1))) const void*)g,
        (__attribute__((address_space(3))) void*)l, 16, 0, 0);
}

// tanh-form GELU: max |err| vs erf-GELU ~3e-4 in h -> ~1e-3 in out (thr 0.026)
__device__ __forceinline__ float gelu_f(float v) {
    float u = 0.7978845608028654f * v * (1.0f + 0.044715f * v * v);
    float t = __expf(-2.0f * fabsf(u));
    float th = (1.0f - t) / (1.0f + t);
    th = (u >= 0.f) ? th : -th;
    return 0.5f * v * (1.0f + th);
}

// ---------------- W [E][R][C] f32 -> Wt [E][C][R] f16 ----------------
__global__ __launch_bounds__(256) void transpose_conv_kernel(
    const float* __restrict__ src, f16* __restrict__ dst, int R, int C)
{
    const float* s = src + (size_t)blockIdx.z * R * C;
    f16* d = dst + (size_t)blockIdx.z * R * C;
    __shared__ float tile[64 * 65];
    const int rb = blockIdx.y * 64, cb = blockIdx.x * 64;
    const int tid = threadIdx.x;
#pragma unroll
    for (int j = 0; j < 4; ++j) {
        int lin = j * 1024 + tid * 4;
        int r = lin >> 6, c = lin & 63;
        float4 v = *(const float4*)(s + (size_t)(rb + r) * C + (cb + c));
        tile[r * 65 + c + 0] = v.x; tile[r * 65 + c + 1] = v.y;
        tile[r * 65 + c + 2] = v.z; tile[r * 65 + c + 3] = v.w;
    }
    __syncthreads();
#pragma unroll
    for (int j = 0; j < 4; ++j) {
        int lin = j * 1024 + tid * 4;
        int c = lin >> 6, r = lin & 63;
        half4 o = { (f16)tile[(r + 0) * 65 + c], (f16)tile[(r + 1) * 65 + c],
                    (f16)tile[(r + 2) * 65 + c], (f16)tile[(r + 3) * 65 + c] };
        *(half4*)(d + (size_t)(cb + c) * R + (rb + r)) = o;
    }
}

// ---------- router (fused x->f16 convert): gates, top-2, stats, xh ----------
__global__ __launch_bounds__(256) void router_kernel(
    const float* __restrict__ x, const float* __restrict__ Wr,
    const float* __restrict__ br,
    int* __restrict__ topk_idx, float* __restrict__ topk_w,
    int* __restrict__ meta, f16* __restrict__ xh)
{
    const int w = threadIdx.x >> 6, l = threadIdx.x & 63;
    __shared__ float blk_sg[E_NUM];
    __shared__ int   blk_cnt[E_NUM];
    if (threadIdx.x < E_NUM) { blk_sg[threadIdx.x] = 0.f; blk_cnt[threadIdx.x] = 0; }
    __syncthreads();

    for (int it = 0; it < 4; ++it) {
        const int t = blockIdx.x * 16 + w * 4 + it;
        const float* xr = x + (size_t)t * D_DIM + l * 16;
        float acc[E_NUM] = {0.f,0.f,0.f,0.f,0.f,0.f,0.f,0.f};
        f16 hx[16];
#pragma unroll
        for (int i = 0; i < 16; i += 4) {
            float4 xv = *(const float4*)(xr + i);
            const float xs[4] = {xv.x, xv.y, xv.z, xv.w};
#pragma unroll
            for (int jj = 0; jj < 4; ++jj) {
                hx[i + jj] = (f16)xs[jj];
                int d = l * 16 + i + jj;
                float4 w0 = *(const float4*)(Wr + (size_t)d * 8);
                float4 w1 = *(const float4*)(Wr + (size_t)d * 8 + 4);
                acc[0] += xs[jj] * w0.x; acc[1] += xs[jj] * w0.y;
                acc[2] += xs[jj] * w0.z; acc[3] += xs[jj] * w0.w;
                acc[4] += xs[jj] * w1.x; acc[5] += xs[jj] * w1.y;
                acc[6] += xs[jj] * w1.z; acc[7] += xs[jj] * w1.w;
            }
        }
        // fused convert: write this row segment as f16
        f16* xo = xh + (size_t)t * D_DIM + l * 16;
        *(half8*)(xo)     = *(const half8*)&hx[0];
        *(half8*)(xo + 8) = *(const half8*)&hx[8];
#pragma unroll
        for (int e = 0; e < E_NUM; ++e) {
#pragma unroll
            for (int off = 32; off > 0; off >>= 1)
                acc[e] += __shfl_down(acc[e], off);
        }
        if (l == 0) {
            float lg[E_NUM], g[E_NUM];
            float mx = -1e30f;
#pragma unroll
            for (int e = 0; e < E_NUM; ++e) { lg[e] = acc[e] + br[e]; mx = fmaxf(mx, lg[e]); }
            float sum = 0.f;
#pragma unroll
            for (int e = 0; e < E_NUM; ++e) { g[e] = __expf(lg[e] - mx); sum += g[e]; }
            float inv = 1.f / sum;
#pragma unroll
            for (int e = 0; e < E_NUM; ++e) g[e] *= inv;
            int e1 = 0; float v1 = g[0];
#pragma unroll
            for (int e = 1; e < E_NUM; ++e) if (g[e] > v1) { v1 = g[e]; e1 = e; }
            int e2 = -1; float v2 = -1.f;
#pragma unroll
            for (int e = 0; e < E_NUM; ++e) if (e != e1 && g[e] > v2) { v2 = g[e]; e2 = e; }
            topk_idx[t * 2 + 0] = e1; topk_idx[t * 2 + 1] = e2;
            topk_w[t * 2 + 0] = v1;   topk_w[t * 2 + 1] = v2;
#pragma unroll
            for (int e = 0; e < E_NUM; ++e) atomicAdd(&blk_sg[e], g[e]);
            atomicAdd(&blk_cnt[e1], 1); atomicAdd(&blk_cnt[e2], 1);
        }
    }
    __syncthreads();
    if (threadIdx.x < E_NUM) {
        atomicAdd((float*)(meta + MI_SUMG) + threadIdx.x, blk_sg[threadIdx.x]);
        atomicAdd(meta + MI_COUNT + threadIdx.x, blk_cnt[threadIdx.x]);
    }
}

// ---------------- scan: offsets (128-padded), rowtile table, aux loss ----------------
__global__ __launch_bounds__(256) void scan_kernel(int* __restrict__ meta, float* __restrict__ out_aux)
{
    __shared__ int offs[E_NUM + 1];
    const int tid = threadIdx.x;
    if (tid == 0) {
        int off = 0;
        for (int e = 0; e < E_NUM; ++e) {
            meta[MI_OFF + e] = off;
            offs[e] = off;
            int cnt = meta[MI_COUNT + e];
            off += ((cnt + 127) >> 7) << 7;
        }
        meta[MI_OFF + E_NUM] = off;
        offs[E_NUM] = off;
        meta[MI_TOTAL] = off >> 7;
        const float* sg = (const float*)(meta + MI_SUMG);
        float aux = 0.f;
        for (int e = 0; e < E_NUM; ++e)
            aux += (sg[e] / (float)N_TOK) * ((float)meta[MI_COUNT + e] / (float)N_TOK);
        out_aux[0] = aux * (float)E_NUM / (float)N_TOK;
    }
    __syncthreads();
    const int total = offs[E_NUM] >> 7;
    for (int rt = tid; rt < total; rt += 256) {
        int row = rt << 7, e = 0;
#pragma unroll
        for (int k = 1; k < E_NUM; ++k) if (row >= offs[k]) e = k;
        meta[MI_RTE + rt] = e;
    }
}

// ---------------- fill compacted slot lists (+ per-token slot map) ----------------
__global__ __launch_bounds__(256) void fill_kernel(
    const int* __restrict__ topk_idx, const float* __restrict__ topk_w,
    int* __restrict__ meta, int* __restrict__ slot_token, float* __restrict__ slot_weight,
    int* __restrict__ slot_of)
{
    int t = blockIdx.x * 256 + threadIdx.x;
#pragma unroll
    for (int k = 0; k < 2; ++k) {
        int e = topk_idx[t * 2 + k];
        int p = atomicAdd(meta + MI_CURSOR + e, 1);
        int slot = meta[MI_OFF + e] + p;
        slot_token[slot] = t;
        slot_weight[slot] = topk_w[t * 2 + k];
        slot_of[t * 2 + k] = slot;
    }
}

// =====================================================================
// m97-proportion GEMM: 128x128 tile, BK=64, 256 threads (4 waves, 2x2
// grid of 64x64 wave tiles), SINGLE-buffered 32 KiB LDS -> up to 5
// blocks/CU. SWZ: chunked XCD swizzle (T1) — ON for gemm2 (B-panel
// streaming regime, proven win), OFF for gemm1 (natural round-robin
// gives best B-reuse; chunked order tripled its FETCH in R10).
// Split-K: kp writes f16 partials at kp*out_kp_stride.
// =====================================================================

template<int KD, int NCOLS, int KSPLIT, bool GATHER, bool GELU, bool BIAS, bool SWZ>
__global__ __launch_bounds__(256, 5) void gemm128_kernel(
    const f16* __restrict__ A, const f16* __restrict__ Bw,
    const float* __restrict__ bias, const int* __restrict__ slot_token,
    const int* __restrict__ meta, f16* __restrict__ Out, size_t out_kp_stride)
{
    constexpr int KLOC = KD / KSPLIT;
    constexpr int NT = KLOC / 64;
    __shared__ __align__(16) f16 As[128 * 64];   // 16 KiB
    __shared__ __align__(16) f16 Bs[128 * 64];   // 16 KiB

    int nt, rt, kp;
    if (SWZ) {
        const int gx = gridDim.x, gy = gridDim.y;
        const int nwg = gx * gy * gridDim.z;
        const int flat = (blockIdx.z * gy + blockIdx.y) * gx + blockIdx.x;
        const int swz = (flat & 7) * (nwg >> 3) + (flat >> 3);
        nt = swz % gx;
        const int tmp = swz / gx;
        rt = tmp % gy;
        kp = tmp / gy;
    } else {
        nt = blockIdx.x; rt = blockIdx.y; kp = blockIdx.z;
    }

    if (rt >= meta[MI_TOTAL]) return;
    const int e  = meta[MI_RTE + rt];
    const int kbase = kp * KLOC;

    const int tid = threadIdx.x;
    const int w = tid >> 6, l = tid & 63;
    const int wr2 = w >> 1, wc2 = w & 1;        // 2 (M) x 2 (N) waves, 64x64 each
    const int fr = l & 15, fq = l >> 4;

    const int srow = tid >> 3;                  // 0..31
    const int kcs  = (tid & 7) ^ (srow & 7);    // pre-swizzled source chunk

    const f16* asrc[4]; const f16* bsrc[4];
#pragma unroll
    for (int i = 0; i < 4; ++i) {
        int r = i * 32 + srow;                  // row within 128-tile
        int ar;
        if (GATHER) ar = slot_token[rt * 128 + r];
        else        ar = rt * 128 + r;
        asrc[i] = A + (size_t)ar * KD + kbase + kcs * 8;
        bsrc[i] = Bw + ((size_t)e * NCOLS + (size_t)nt * 128 + r) * KD + kbase + kcs * 8;
    }

    const int rA  = wr2 * 64 + fr;
    const int rB  = wc2 * 64 + fr;
    const int sw0 = ( fq      ^ (fr & 7)) * 8;  // swizzled chunk offsets (f16 units), kk=0
    const int sw1 = ((4 + fq) ^ (fr & 7)) * 8;  // kk=32

    floatx4 acc[4][4];
#pragma unroll
    for (int m = 0; m < 4; ++m)
#pragma unroll
        for (int n = 0; n < 4; ++n) acc[m][n] = (floatx4){0.f, 0.f, 0.f, 0.f};

    half8 af[4], bf[4];

#pragma unroll 2
    for (int t = 0; t < NT; ++t) {
        // stage tile t (single buffer)
#pragma unroll
        for (int i = 0; i < 4; ++i) {
            gld_lds16(asrc[i] + (size_t)t * 64, &As[i * 2048 + tid * 8]);
            gld_lds16(bsrc[i] + (size_t)t * 64, &Bs[i * 2048 + tid * 8]);
        }
        asm volatile("s_waitcnt vmcnt(0)" ::: "memory");
        __builtin_amdgcn_s_barrier();
        // compute: 2 kk-halves x (8 ds_read + 16 MFMA)
#pragma unroll
        for (int kk2 = 0; kk2 < 2; ++kk2) {
            const int sw = kk2 ? sw1 : sw0;
#pragma unroll
            for (int mj = 0; mj < 4; ++mj)
                af[mj] = *(const half8*)&As[(size_t)(rA + mj * 16) * 64 + sw];
#pragma unroll
            for (int nj = 0; nj < 4; ++nj)
                bf[nj] = *(const half8*)&Bs[(size_t)(rB + nj * 16) * 64 + sw];
#pragma unroll
            for (int mj = 0; mj < 4; ++mj)
#pragma unroll
                for (int nj = 0; nj < 4; ++nj)
                    acc[mj][nj] = __builtin_amdgcn_mfma_f32_16x16x32_f16(
                        af[mj], bf[nj], acc[mj][nj], 0, 0, 0);
        }
        __builtin_amdgcn_s_barrier();   // all reads consumed before next stage
    }

    // ---- epilogue: 64 outputs/thread ----
    f16* Op = Out + (size_t)kp * out_kp_stride;
    const int orow0 = rt * 128 + wr2 * 64;
    const int ocol0 = nt * 128 + wc2 * 64;
#pragma unroll
    for (int mj = 0; mj < 4; ++mj) {
#pragma unroll
        for (int nj = 0; nj < 4; ++nj) {
            const int col = ocol0 + nj * 16 + fr;
            float bs = 0.f;
            if (BIAS) bs = bias[(size_t)e * NCOLS + col];
#pragma unroll
            for (int j = 0; j < 4; ++j) {
                const int row = orow0 + mj * 16 + fq * 4 + j;
                float v = acc[mj][nj][j] + bs;
                if (GELU) v = gelu_f(v);
                Op[(size_t)row * NCOLS + col] = (f16)v;
            }
        }
    }
}

// ------- combine: out[t] = w0*(P0[s0]+P1[s0]+b2[e0]) + w1*(P0[s1]+P1[s1]+b2[e1]) -------
__global__ __launch_bounds__(256) void combine_kernel(
    const f16* __restrict__ P, const int* __restrict__ slot_of,
    const int* __restrict__ topk_idx, const float* __restrict__ topk_w,
    const float* __restrict__ b2, float* __restrict__ out)
{
    const int t = blockIdx.x;
    const int c = threadIdx.x;          // 256 threads x 4 cols
    const size_t PS = (size_t)MAX_SLOTS * D_DIM;
    const int s0 = slot_of[t * 2], s1 = slot_of[t * 2 + 1];
    const int e0 = topk_idx[t * 2], e1 = topk_idx[t * 2 + 1];
    const float w0 = topk_w[t * 2], w1 = topk_w[t * 2 + 1];
    half4 a0 = *(const half4*)(P + (size_t)s0 * D_DIM + c * 4);
    half4 a1 = *(const half4*)(P + PS + (size_t)s0 * D_DIM + c * 4);
    half4 c0 = *(const half4*)(P + (size_t)s1 * D_DIM + c * 4);
    half4 c1 = *(const half4*)(P + PS + (size_t)s1 * D_DIM + c * 4);
    float4 bb0 = *(const float4*)(b2 + (size_t)e0 * D_DIM + c * 4);
    float4 bb1 = *(const float4*)(b2 + (size_t)e1 * D_DIM + c * 4);
    float4 o;
    o.x = w0 * ((float)a0[0] + (float)a1[0] + bb0.x) + w1 * ((float)c0[0] + (float)c1[0] + bb1.x);
    o.y = w0 * ((float)a0[1] + (float)a1[1] + bb0.y) + w1 * ((float)c0[1] + (float)c1[1] + bb1.y);
    o.z = w0 * ((float)a0[2] + (float)a1[2] + bb0.z) + w1 * ((float)c0[2] + (float)c1[2] + bb1.z);
    o.w = w0 * ((float)a0[3] + (float)a1[3] + bb0.w) + w1 * ((float)c0[3] + (float)c1[3] + bb1.w);
    *(float4*)(out + (size_t)t * D_DIM + c * 4) = o;
}

extern "C" void kernel_launch(void* const* d_in, const int* in_sizes, int n_in,
                              void* d_out, int out_size, void* d_ws, size_t ws_size,
                              hipStream_t stream) {
    const float* x  = (const float*)d_in[0];
    const float* Wr = (const float*)d_in[1];
    const float* br = (const float*)d_in[2];
    const float* W1 = (const float*)d_in[3];
    const float* b1 = (const float*)d_in[4];
    const float* W2 = (const float*)d_in[5];
    const float* b2 = (const float*)d_in[6];
    float* out = (float*)d_out;

    char* ws = (char*)d_ws;
    const size_t SZ_XH  = (size_t)N_TOK * D_DIM * 2;          // 16 MiB
    const size_t SZ_W1T = (size_t)E_NUM * DF_DIM * D_DIM * 2; // 64 MiB
    const size_t SZ_W2T = SZ_W1T;
    const size_t SZ_H   = (size_t)MAX_SLOTS * DF_DIM * 2;     // 136 MiB

    f16* xh  = (f16*)(ws);
    f16* W1t = (f16*)(ws + SZ_XH);
    f16* W2t = (f16*)(ws + SZ_XH + SZ_W1T);
    f16* H   = (f16*)(ws + SZ_XH + SZ_W1T + SZ_W2T);
    // P (2 split-K partials, 34 MiB each) aliases [xh | W1t] (80 MiB) — dead after gemm1.
    f16* P   = (f16*)ws;
    char* p  = ws + SZ_XH + SZ_W1T + SZ_W2T + SZ_H;
    int*   topk_idx    = (int*)p;    p += (size_t)N_TOK * 2 * 4;
    float* topk_w      = (float*)p;  p += (size_t)N_TOK * 2 * 4;
    int*   slot_token  = (int*)p;    p += (size_t)MAX_SLOTS * 4;
    float* slot_weight = (float*)p;  p += (size_t)MAX_SLOTS * 4;
    int*   slot_of     = (int*)p;    p += (size_t)N_TOK * 2 * 4;
    int*   meta        = (int*)p;

    // per-call init: zero slot lists (pad slots -> token 0 / weight 0) + slot_of + meta
    hipMemsetAsync(slot_token, 0, (size_t)MAX_SLOTS * 8 + (size_t)N_TOK * 2 * 4 + 1024, stream);

    transpose_conv_kernel<<<dim3(DF_DIM / 64, D_DIM / 64, E_NUM), 256, 0, stream>>>(W1, W1t, D_DIM, DF_DIM);
    transpose_conv_kernel<<<dim3(D_DIM / 64, DF_DIM / 64, E_NUM), 256, 0, stream>>>(W2, W2t, DF_DIM, D_DIM);
    router_kernel<<<N_TOK / 16, 256, 0, stream>>>(x, Wr, br, topk_idx, topk_w, meta, xh);
    scan_kernel<<<1, 256, 0, stream>>>(meta, out + (size_t)N_TOK * D_DIM);
    fill_kernel<<<N_TOK / 256, 256, 0, stream>>>(topk_idx, topk_w, meta, slot_token, slot_weight, slot_of);

    // GEMM1 (m97-style 128-tile, natural order): H = gelu(gather(xh) @ W1t + b1)
    gemm128_kernel<D_DIM, DF_DIM, 1, true, true, true, false>
        <<<dim3(DF_DIM / 128, MAX_RT, 1), 256, 0, stream>>>(
        xh, W1t, b1, slot_token, meta, H, 0);

    // GEMM2 (m97-style 128-tile, XCD swizzle, split-K=2): P[kp] = H @ W2t
    gemm128_kernel<DF_DIM, D_DIM, 2, false, false, false, true>
        <<<dim3(D_DIM / 128, MAX_RT, 2), 256, 0, stream>>>(
        H, W2t, nullptr, slot_token, meta, P, (size_t)MAX_SLOTS * D_DIM);

    combine_kernel<<<N_TOK, 256, 0, stream>>>(P, slot_of, topk_idx, topk_w, b2, out);

    (void)in_sizes; (void)n_in; (void)ws_size;
}

// Round 12
// 560.377 us; speedup vs baseline: 2.7831x; 2.7831x over previous
//
#include <hip/hip_runtime.h>
#include <hip/hip_bf16.h>
#include <hip/hip_fp16.h>

typedef _Float16 f16;
typedef _Float16 half8 __attribute__((ext_vector_type(8)));
typedef _Float16 half4 __attribute__((ext_vector_type(4)));
typedef float   floatx4 __attribute__((ext_vector_type(4)));

#define N_TOK   8192
#define D_DIM   1024
#define E_NUM   8
#define DF_DIM  4096
#define MAX_SLOTS 17408   // 16384 + 8*128 padding
#define MAX_RT    136     // MAX_SLOTS / 128

// meta layout (int32 indices)
#define MI_COUNT  0    // [8]
#define MI_CURSOR 8    // [8]
#define MI_OFF    16   // [9]
#define MI_TOTAL  25   // [1]  (# of 128-row tiles)
#define MI_RTE    26   // [136]
#define MI_SUMG   168  // [8] floats

__device__ __forceinline__ void gld_lds16(const void* g, void* l) {
    __builtin_amdgcn_global_load_lds(
        (__attribute__((address_space(1))) const void*)g,
        (__attribute__((address_space(3))) void*)l, 16, 0, 0);
}

// tanh-form GELU: max |err| vs erf-GELU ~3e-4 in h -> ~1e-3 in out (thr 0.026)
__device__ __forceinline__ float gelu_f(float v) {
    float u = 0.7978845608028654f * v * (1.0f + 0.044715f * v * v);
    float t = __expf(-2.0f * fabsf(u));
    float th = (1.0f - t) / (1.0f + t);
    th = (u >= 0.f) ? th : -th;
    return 0.5f * v * (1.0f + th);
}

// ---------------- W [E][R][C] f32 -> Wt [E][C][R] f16 ----------------
__global__ __launch_bounds__(256) void transpose_conv_kernel(
    const float* __restrict__ src, f16* __restrict__ dst, int R, int C)
{
    const float* s = src + (size_t)blockIdx.z * R * C;
    f16* d = dst + (size_t)blockIdx.z * R * C;
    __shared__ float tile[64 * 65];
    const int rb = blockIdx.y * 64, cb = blockIdx.x * 64;
    const int tid = threadIdx.x;
#pragma unroll
    for (int j = 0; j < 4; ++j) {
        int lin = j * 1024 + tid * 4;
        int r = lin >> 6, c = lin & 63;
        float4 v = *(const float4*)(s + (size_t)(rb + r) * C + (cb + c));
        tile[r * 65 + c + 0] = v.x; tile[r * 65 + c + 1] = v.y;
        tile[r * 65 + c + 2] = v.z; tile[r * 65 + c + 3] = v.w;
    }
    __syncthreads();
#pragma unroll
    for (int j = 0; j < 4; ++j) {
        int lin = j * 1024 + tid * 4;
        int c = lin >> 6, r = lin & 63;
        half4 o = { (f16)tile[(r + 0) * 65 + c], (f16)tile[(r + 1) * 65 + c],
                    (f16)tile[(r + 2) * 65 + c], (f16)tile[(r + 3) * 65 + c] };
        *(half4*)(d + (size_t)(cb + c) * R + (rb + r)) = o;
    }
}

// ---------- router (fused x->f16 convert): gates, top-2, stats, xh ----------
__global__ __launch_bounds__(256) void router_kernel(
    const float* __restrict__ x, const float* __restrict__ Wr,
    const float* __restrict__ br,
    int* __restrict__ topk_idx, float* __restrict__ topk_w,
    int* __restrict__ meta, f16* __restrict__ xh)
{
    const int w = threadIdx.x >> 6, l = threadIdx.x & 63;
    __shared__ float blk_sg[E_NUM];
    __shared__ int   blk_cnt[E_NUM];
    if (threadIdx.x < E_NUM) { blk_sg[threadIdx.x] = 0.f; blk_cnt[threadIdx.x] = 0; }
    __syncthreads();

    for (int it = 0; it < 4; ++it) {
        const int t = blockIdx.x * 16 + w * 4 + it;
        const float* xr = x + (size_t)t * D_DIM + l * 16;
        float acc[E_NUM] = {0.f,0.f,0.f,0.f,0.f,0.f,0.f,0.f};
        f16 hx[16];
#pragma unroll
        for (int i = 0; i < 16; i += 4) {
            float4 xv = *(const float4*)(xr + i);
            const float xs[4] = {xv.x, xv.y, xv.z, xv.w};
#pragma unroll
            for (int jj = 0; jj < 4; ++jj) {
                hx[i + jj] = (f16)xs[jj];
                int d = l * 16 + i + jj;
                float4 w0 = *(const float4*)(Wr + (size_t)d * 8);
                float4 w1 = *(const float4*)(Wr + (size_t)d * 8 + 4);
                acc[0] += xs[jj] * w0.x; acc[1] += xs[jj] * w0.y;
                acc[2] += xs[jj] * w0.z; acc[3] += xs[jj] * w0.w;
                acc[4] += xs[jj] * w1.x; acc[5] += xs[jj] * w1.y;
                acc[6] += xs[jj] * w1.z; acc[7] += xs[jj] * w1.w;
            }
        }
        // fused convert: write this row segment as f16
        f16* xo = xh + (size_t)t * D_DIM + l * 16;
        *(half8*)(xo)     = *(const half8*)&hx[0];
        *(half8*)(xo + 8) = *(const half8*)&hx[8];
#pragma unroll
        for (int e = 0; e < E_NUM; ++e) {
#pragma unroll
            for (int off = 32; off > 0; off >>= 1)
                acc[e] += __shfl_down(acc[e], off);
        }
        if (l == 0) {
            float lg[E_NUM], g[E_NUM];
            float mx = -1e30f;
#pragma unroll
            for (int e = 0; e < E_NUM; ++e) { lg[e] = acc[e] + br[e]; mx = fmaxf(mx, lg[e]); }
            float sum = 0.f;
#pragma unroll
            for (int e = 0; e < E_NUM; ++e) { g[e] = __expf(lg[e] - mx); sum += g[e]; }
            float inv = 1.f / sum;
#pragma unroll
            for (int e = 0; e < E_NUM; ++e) g[e] *= inv;
            int e1 = 0; float v1 = g[0];
#pragma unroll
            for (int e = 1; e < E_NUM; ++e) if (g[e] > v1) { v1 = g[e]; e1 = e; }
            int e2 = -1; float v2 = -1.f;
#pragma unroll
            for (int e = 0; e < E_NUM; ++e) if (e != e1 && g[e] > v2) { v2 = g[e]; e2 = e; }
            topk_idx[t * 2 + 0] = e1; topk_idx[t * 2 + 1] = e2;
            topk_w[t * 2 + 0] = v1;   topk_w[t * 2 + 1] = v2;
#pragma unroll
            for (int e = 0; e < E_NUM; ++e) atomicAdd(&blk_sg[e], g[e]);
            atomicAdd(&blk_cnt[e1], 1); atomicAdd(&blk_cnt[e2], 1);
        }
    }
    __syncthreads();
    if (threadIdx.x < E_NUM) {
        atomicAdd((float*)(meta + MI_SUMG) + threadIdx.x, blk_sg[threadIdx.x]);
        atomicAdd(meta + MI_COUNT + threadIdx.x, blk_cnt[threadIdx.x]);
    }
}

// ---------------- scan: offsets (128-padded), rowtile table, aux loss ----------------
__global__ __launch_bounds__(256) void scan_kernel(int* __restrict__ meta, float* __restrict__ out_aux)
{
    __shared__ int offs[E_NUM + 1];
    const int tid = threadIdx.x;
    if (tid == 0) {
        int off = 0;
        for (int e = 0; e < E_NUM; ++e) {
            meta[MI_OFF + e] = off;
            offs[e] = off;
            int cnt = meta[MI_COUNT + e];
            off += ((cnt + 127) >> 7) << 7;
        }
        meta[MI_OFF + E_NUM] = off;
        offs[E_NUM] = off;
        meta[MI_TOTAL] = off >> 7;
        const float* sg = (const float*)(meta + MI_SUMG);
        float aux = 0.f;
        for (int e = 0; e < E_NUM; ++e)
            aux += (sg[e] / (float)N_TOK) * ((float)meta[MI_COUNT + e] / (float)N_TOK);
        out_aux[0] = aux * (float)E_NUM / (float)N_TOK;
    }
    __syncthreads();
    const int total = offs[E_NUM] >> 7;
    for (int rt = tid; rt < total; rt += 256) {
        int row = rt << 7, e = 0;
#pragma unroll
        for (int k = 1; k < E_NUM; ++k) if (row >= offs[k]) e = k;
        meta[MI_RTE + rt] = e;
    }
}

// ---------------- fill compacted slot lists (+ per-token slot map) ----------------
__global__ __launch_bounds__(256) void fill_kernel(
    const int* __restrict__ topk_idx, const float* __restrict__ topk_w,
    int* __restrict__ meta, int* __restrict__ slot_token, float* __restrict__ slot_weight,
    int* __restrict__ slot_of)
{
    int t = blockIdx.x * 256 + threadIdx.x;
#pragma unroll
    for (int k = 0; k < 2; ++k) {
        int e = topk_idx[t * 2 + k];
        int p = atomicAdd(meta + MI_CURSOR + e, 1);
        int slot = meta[MI_OFF + e] + p;
        slot_token[slot] = t;
        slot_weight[slot] = topk_w[t * 2 + k];
        slot_of[t * 2 + k] = slot;
    }
}

// =====================================================================
// m97-proportion GEMM: 128x128 tile, BK=64, 256 threads (4 waves, 2x2
// grid of 64x64 wave tiles), SINGLE-buffered 32 KiB LDS.
// __launch_bounds__(256,4): 4 waves/EU -> 4 blocks/CU, VGPR budget 128
// (acc[4][4]=64 VGPRs fits; (256,5) capped at ~102 and SPILLED the
// accumulator -> R11's 2.7x regression. Do not raise this again.)
// SWZ: chunked XCD swizzle (T1) — ON for gemm2 (proven win), OFF for
// gemm1 (natural round-robin gives best B-reuse; chunked tripled FETCH).
// Split-K: kp writes f16 partials at kp*out_kp_stride.
// =====================================================================

template<int KD, int NCOLS, int KSPLIT, bool GATHER, bool GELU, bool BIAS, bool SWZ>
__global__ __launch_bounds__(256, 4) void gemm128_kernel(
    const f16* __restrict__ A, const f16* __restrict__ Bw,
    const float* __restrict__ bias, const int* __restrict__ slot_token,
    const int* __restrict__ meta, f16* __restrict__ Out, size_t out_kp_stride)
{
    constexpr int KLOC = KD / KSPLIT;
    constexpr int NT = KLOC / 64;
    __shared__ __align__(16) f16 As[128 * 64];   // 16 KiB
    __shared__ __align__(16) f16 Bs[128 * 64];   // 16 KiB

    int nt, rt, kp;
    if (SWZ) {
        const int gx = gridDim.x, gy = gridDim.y;
        const int nwg = gx * gy * gridDim.z;
        const int flat = (blockIdx.z * gy + blockIdx.y) * gx + blockIdx.x;
        const int swz = (flat & 7) * (nwg >> 3) + (flat >> 3);
        nt = swz % gx;
        const int tmp = swz / gx;
        rt = tmp % gy;
        kp = tmp / gy;
    } else {
        nt = blockIdx.x; rt = blockIdx.y; kp = blockIdx.z;
    }

    if (rt >= meta[MI_TOTAL]) return;
    const int e  = meta[MI_RTE + rt];
    const int kbase = kp * KLOC;

    const int tid = threadIdx.x;
    const int w = tid >> 6, l = tid & 63;
    const int wr2 = w >> 1, wc2 = w & 1;        // 2 (M) x 2 (N) waves, 64x64 each
    const int fr = l & 15, fq = l >> 4;

    const int srow = tid >> 3;                  // 0..31
    const int kcs  = (tid & 7) ^ (srow & 7);    // pre-swizzled source chunk

    const f16* asrc[4]; const f16* bsrc[4];
#pragma unroll
    for (int i = 0; i < 4; ++i) {
        int r = i * 32 + srow;                  // row within 128-tile
        int ar;
        if (GATHER) ar = slot_token[rt * 128 + r];
        else        ar = rt * 128 + r;
        asrc[i] = A + (size_t)ar * KD + kbase + kcs * 8;
        bsrc[i] = Bw + ((size_t)e * NCOLS + (size_t)nt * 128 + r) * KD + kbase + kcs * 8;
    }

    const int rA  = wr2 * 64 + fr;
    const int rB  = wc2 * 64 + fr;
    const int sw0 = ( fq      ^ (fr & 7)) * 8;  // swizzled chunk offsets (f16 units), kk=0
    const int sw1 = ((4 + fq) ^ (fr & 7)) * 8;  // kk=32

    floatx4 acc[4][4];
#pragma unroll
    for (int m = 0; m < 4; ++m)
#pragma unroll
        for (int n = 0; n < 4; ++n) acc[m][n] = (floatx4){0.f, 0.f, 0.f, 0.f};

    half8 af[4], bf[4];

#pragma unroll 2
    for (int t = 0; t < NT; ++t) {
        // stage tile t (single buffer)
#pragma unroll
        for (int i = 0; i < 4; ++i) {
            gld_lds16(asrc[i] + (size_t)t * 64, &As[i * 2048 + tid * 8]);
            gld_lds16(bsrc[i] + (size_t)t * 64, &Bs[i * 2048 + tid * 8]);
        }
        asm volatile("s_waitcnt vmcnt(0)" ::: "memory");
        __builtin_amdgcn_s_barrier();
        // compute: 2 kk-halves x (8 ds_read + 16 MFMA)
#pragma unroll
        for (int kk2 = 0; kk2 < 2; ++kk2) {
            const int sw = kk2 ? sw1 : sw0;
#pragma unroll
            for (int mj = 0; mj < 4; ++mj)
                af[mj] = *(const half8*)&As[(size_t)(rA + mj * 16) * 64 + sw];
#pragma unroll
            for (int nj = 0; nj < 4; ++nj)
                bf[nj] = *(const half8*)&Bs[(size_t)(rB + nj * 16) * 64 + sw];
#pragma unroll
            for (int mj = 0; mj < 4; ++mj)
#pragma unroll
                for (int nj = 0; nj < 4; ++nj)
                    acc[mj][nj] = __builtin_amdgcn_mfma_f32_16x16x32_f16(
                        af[mj], bf[nj], acc[mj][nj], 0, 0, 0);
        }
        __builtin_amdgcn_s_barrier();   // all reads consumed before next stage
    }

    // ---- epilogue: 64 outputs/thread ----
    f16* Op = Out + (size_t)kp * out_kp_stride;
    const int orow0 = rt * 128 + wr2 * 64;
    const int ocol0 = nt * 128 + wc2 * 64;
#pragma unroll
    for (int mj = 0; mj < 4; ++mj) {
#pragma unroll
        for (int nj = 0; nj < 4; ++nj) {
            const int col = ocol0 + nj * 16 + fr;
            float bs = 0.f;
            if (BIAS) bs = bias[(size_t)e * NCOLS + col];
#pragma unroll
            for (int j = 0; j < 4; ++j) {
                const int row = orow0 + mj * 16 + fq * 4 + j;
                float v = acc[mj][nj][j] + bs;
                if (GELU) v = gelu_f(v);
                Op[(size_t)row * NCOLS + col] = (f16)v;
            }
        }
    }
}

// ------- combine: out[t] = w0*(P0[s0]+P1[s0]+b2[e0]) + w1*(P0[s1]+P1[s1]+b2[e1]) -------
__global__ __launch_bounds__(256) void combine_kernel(
    const f16* __restrict__ P, const int* __restrict__ slot_of,
    const int* __restrict__ topk_idx, const float* __restrict__ topk_w,
    const float* __restrict__ b2, float* __restrict__ out)
{
    const int t = blockIdx.x;
    const int c = threadIdx.x;          // 256 threads x 4 cols
    const size_t PS = (size_t)MAX_SLOTS * D_DIM;
    const int s0 = slot_of[t * 2], s1 = slot_of[t * 2 + 1];
    const int e0 = topk_idx[t * 2], e1 = topk_idx[t * 2 + 1];
    const float w0 = topk_w[t * 2], w1 = topk_w[t * 2 + 1];
    half4 a0 = *(const half4*)(P + (size_t)s0 * D_DIM + c * 4);
    half4 a1 = *(const half4*)(P + PS + (size_t)s0 * D_DIM + c * 4);
    half4 c0 = *(const half4*)(P + (size_t)s1 * D_DIM + c * 4);
    half4 c1 = *(const half4*)(P + PS + (size_t)s1 * D_DIM + c * 4);
    float4 bb0 = *(const float4*)(b2 + (size_t)e0 * D_DIM + c * 4);
    float4 bb1 = *(const float4*)(b2 + (size_t)e1 * D_DIM + c * 4);
    float4 o;
    o.x = w0 * ((float)a0[0] + (float)a1[0] + bb0.x) + w1 * ((float)c0[0] + (float)c1[0] + bb1.x);
    o.y = w0 * ((float)a0[1] + (float)a1[1] + bb0.y) + w1 * ((float)c0[1] + (float)c1[1] + bb1.y);
    o.z = w0 * ((float)a0[2] + (float)a1[2] + bb0.z) + w1 * ((float)c0[2] + (float)c1[2] + bb1.z);
    o.w = w0 * ((float)a0[3] + (float)a1[3] + bb0.w) + w1 * ((float)c0[3] + (float)c1[3] + bb1.w);
    *(float4*)(out + (size_t)t * D_DIM + c * 4) = o;
}

extern "C" void kernel_launch(void* const* d_in, const int* in_sizes, int n_in,
                              void* d_out, int out_size, void* d_ws, size_t ws_size,
                              hipStream_t stream) {
    const float* x  = (const float*)d_in[0];
    const float* Wr = (const float*)d_in[1];
    const float* br = (const float*)d_in[2];
    const float* W1 = (const float*)d_in[3];
    const float* b1 = (const float*)d_in[4];
    const float* W2 = (const float*)d_in[5];
    const float* b2 = (const float*)d_in[6];
    float* out = (float*)d_out;

    char* ws = (char*)d_ws;
    const size_t SZ_XH  = (size_t)N_TOK * D_DIM * 2;          // 16 MiB
    const size_t SZ_W1T = (size_t)E_NUM * DF_DIM * D_DIM * 2; // 64 MiB
    const size_t SZ_W2T = SZ_W1T;
    const size_t SZ_H   = (size_t)MAX_SLOTS * DF_DIM * 2;     // 136 MiB

    f16* xh  = (f16*)(ws);
    f16* W1t = (f16*)(ws + SZ_XH);
    f16* W2t = (f16*)(ws + SZ_XH + SZ_W1T);
    f16* H   = (f16*)(ws + SZ_XH + SZ_W1T + SZ_W2T);
    // P (2 split-K partials, 34 MiB each) aliases [xh | W1t] (80 MiB) — dead after gemm1.
    f16* P   = (f16*)ws;
    char* p  = ws + SZ_XH + SZ_W1T + SZ_W2T + SZ_H;
    int*   topk_idx    = (int*)p;    p += (size_t)N_TOK * 2 * 4;
    float* topk_w      = (float*)p;  p += (size_t)N_TOK * 2 * 4;
    int*   slot_token  = (int*)p;    p += (size_t)MAX_SLOTS * 4;
    float* slot_weight = (float*)p;  p += (size_t)MAX_SLOTS * 4;
    int*   slot_of     = (int*)p;    p += (size_t)N_TOK * 2 * 4;
    int*   meta        = (int*)p;

    // per-call init: zero slot lists (pad slots -> token 0 / weight 0) + slot_of + meta
    hipMemsetAsync(slot_token, 0, (size_t)MAX_SLOTS * 8 + (size_t)N_TOK * 2 * 4 + 1024, stream);

    transpose_conv_kernel<<<dim3(DF_DIM / 64, D_DIM / 64, E_NUM), 256, 0, stream>>>(W1, W1t, D_DIM, DF_DIM);
    transpose_conv_kernel<<<dim3(D_DIM / 64, DF_DIM / 64, E_NUM), 256, 0, stream>>>(W2, W2t, DF_DIM, D_DIM);
    router_kernel<<<N_TOK / 16, 256, 0, stream>>>(x, Wr, br, topk_idx, topk_w, meta, xh);
    scan_kernel<<<1, 256, 0, stream>>>(meta, out + (size_t)N_TOK * D_DIM);
    fill_kernel<<<N_TOK / 256, 256, 0, stream>>>(topk_idx, topk_w, meta, slot_token, slot_weight, slot_of);

    // GEMM1 (m97-style 128-tile, natural order): H = gelu(gather(xh) @ W1t + b1)
    gemm128_kernel<D_DIM, DF_DIM, 1, true, true, true, false>
        <<<dim3(DF_DIM / 128, MAX_RT, 1), 256, 0, stream>>>(
        xh, W1t, b1, slot_token, meta, H, 0);

    // GEMM2 (m97-style 128-tile, XCD swizzle, split-K=2): P[kp] = H @ W2t
    gemm128_kernel<DF_DIM, D_DIM, 2, false, false, false, true>
        <<<dim3(D_DIM / 128, MAX_RT, 2), 256, 0, stream>>>(
        H, W2t, nullptr, slot_token, meta, P, (size_t)MAX_SLOTS * D_DIM);

    combine_kernel<<<N_TOK, 256, 0, stream>>>(P, slot_of, topk_idx, topk_w, b2, out);

    (void)in_sizes; (void)n_in; (void)ws_size;
}

// Round 13
// 552.238 us; speedup vs baseline: 2.8241x; 1.0147x over previous
//
#include <hip/hip_runtime.h>
#include <hip/hip_bf16.h>
#include <hip/hip_fp16.h>

typedef _Float16 f16;
typedef _Float16 half8 __attribute__((ext_vector_type(8)));
typedef _Float16 half4 __attribute__((ext_vector_type(4)));
typedef float   floatx4 __attribute__((ext_vector_type(4)));

#define N_TOK   8192
#define D_DIM   1024
#define E_NUM   8
#define DF_DIM  4096
#define MAX_SLOTS 17408   // 16384 + 8*128 padding
#define MAX_RT    136     // MAX_SLOTS / 128

// meta layout (int32 indices)
#define MI_COUNT  0    // [8]
#define MI_CURSOR 8    // [8]
#define MI_OFF    16   // [9]
#define MI_TOTAL  25   // [1]  (# of 128-row tiles)
#define MI_RTE    26   // [136]
#define MI_SUMG   168  // [8] floats

__device__ __forceinline__ void gld_lds16(const void* g, void* l) {
    __builtin_amdgcn_global_load_lds(
        (__attribute__((address_space(1))) const void*)g,
        (__attribute__((address_space(3))) void*)l, 16, 0, 0);
}

// tanh-form GELU: max |err| vs erf-GELU ~3e-4 in h -> ~1e-3 in out (thr 0.026)
__device__ __forceinline__ float gelu_f(float v) {
    float u = 0.7978845608028654f * v * (1.0f + 0.044715f * v * v);
    float t = __expf(-2.0f * fabsf(u));
    float th = (1.0f - t) / (1.0f + t);
    th = (u >= 0.f) ? th : -th;
    return 0.5f * v * (1.0f + th);
}

// =====================================================================
// prep_kernel: ONE launch covering three independent preprocessing jobs
//   blocks [0, 8192)        : transpose+convert W1 [D][DF] -> W1t [DF][D]
//   blocks [8192, 16384)    : transpose+convert W2 [DF][D] -> W2t [D][DF]
//   blocks [16384, 16896)   : router (fused x->f16 convert)
// Merging kills 2 launch gaps and packs the three kernels' ragged tails.
// =====================================================================

__device__ __forceinline__ void transpose_tile(
    const float* __restrict__ src, f16* __restrict__ dst, int R, int C,
    int rb, int cb, float* tile /* [64*65] LDS */)
{
    const int tid = threadIdx.x;
#pragma unroll
    for (int j = 0; j < 4; ++j) {
        int lin = j * 1024 + tid * 4;
        int r = lin >> 6, c = lin & 63;
        float4 v = *(const float4*)(src + (size_t)(rb + r) * C + (cb + c));
        tile[r * 65 + c + 0] = v.x; tile[r * 65 + c + 1] = v.y;
        tile[r * 65 + c + 2] = v.z; tile[r * 65 + c + 3] = v.w;
    }
    __syncthreads();
#pragma unroll
    for (int j = 0; j < 4; ++j) {
        int lin = j * 1024 + tid * 4;
        int c = lin >> 6, r = lin & 63;
        half4 o = { (f16)tile[(r + 0) * 65 + c], (f16)tile[(r + 1) * 65 + c],
                    (f16)tile[(r + 2) * 65 + c], (f16)tile[(r + 3) * 65 + c] };
        *(half4*)(dst + (size_t)(cb + c) * R + (rb + r)) = o;
    }
}

__global__ __launch_bounds__(256) void prep_kernel(
    const float* __restrict__ W1, const float* __restrict__ W2,
    f16* __restrict__ W1t, f16* __restrict__ W2t,
    const float* __restrict__ x, const float* __restrict__ Wr,
    const float* __restrict__ br,
    int* __restrict__ topk_idx, float* __restrict__ topk_w,
    int* __restrict__ meta, f16* __restrict__ xh)
{
    __shared__ float tile[64 * 65];
    __shared__ float blk_sg[E_NUM];
    __shared__ int   blk_cnt[E_NUM];

    const int bid = blockIdx.x;
    if (bid < 8192) {
        // ---- transpose W1: R=D, C=DF, grid (64, 16, 8) flattened ----
        const int cx = bid & 63, ry = (bid >> 6) & 15, ez = bid >> 10;
        transpose_tile(W1 + (size_t)ez * D_DIM * DF_DIM,
                       W1t + (size_t)ez * D_DIM * DF_DIM,
                       D_DIM, DF_DIM, ry * 64, cx * 64, tile);
        return;
    }
    if (bid < 16384) {
        // ---- transpose W2: R=DF, C=D, grid (16, 64, 8) flattened ----
        const int id = bid - 8192;
        const int cx = id & 15, ry = (id >> 4) & 63, ez = id >> 10;
        transpose_tile(W2 + (size_t)ez * D_DIM * DF_DIM,
                       W2t + (size_t)ez * D_DIM * DF_DIM,
                       DF_DIM, D_DIM, ry * 64, cx * 64, tile);
        return;
    }

    // ---- router (fused x->f16 convert): 512 blocks x 16 tokens ----
    const int rb = bid - 16384;
    const int w = threadIdx.x >> 6, l = threadIdx.x & 63;
    if (threadIdx.x < E_NUM) { blk_sg[threadIdx.x] = 0.f; blk_cnt[threadIdx.x] = 0; }
    __syncthreads();

    for (int it = 0; it < 4; ++it) {
        const int t = rb * 16 + w * 4 + it;
        const float* xr = x + (size_t)t * D_DIM + l * 16;
        float acc[E_NUM] = {0.f,0.f,0.f,0.f,0.f,0.f,0.f,0.f};
        f16 hx[16];
#pragma unroll
        for (int i = 0; i < 16; i += 4) {
            float4 xv = *(const float4*)(xr + i);
            const float xs[4] = {xv.x, xv.y, xv.z, xv.w};
#pragma unroll
            for (int jj = 0; jj < 4; ++jj) {
                hx[i + jj] = (f16)xs[jj];
                int d = l * 16 + i + jj;
                float4 w0 = *(const float4*)(Wr + (size_t)d * 8);
                float4 w1 = *(const float4*)(Wr + (size_t)d * 8 + 4);
                acc[0] += xs[jj] * w0.x; acc[1] += xs[jj] * w0.y;
                acc[2] += xs[jj] * w0.z; acc[3] += xs[jj] * w0.w;
                acc[4] += xs[jj] * w1.x; acc[5] += xs[jj] * w1.y;
                acc[6] += xs[jj] * w1.z; acc[7] += xs[jj] * w1.w;
            }
        }
        // fused convert: write this row segment as f16
        f16* xo = xh + (size_t)t * D_DIM + l * 16;
        *(half8*)(xo)     = *(const half8*)&hx[0];
        *(half8*)(xo + 8) = *(const half8*)&hx[8];
#pragma unroll
        for (int e = 0; e < E_NUM; ++e) {
#pragma unroll
            for (int off = 32; off > 0; off >>= 1)
                acc[e] += __shfl_down(acc[e], off);
        }
        if (l == 0) {
            float lg[E_NUM], g[E_NUM];
            float mx = -1e30f;
#pragma unroll
            for (int e = 0; e < E_NUM; ++e) { lg[e] = acc[e] + br[e]; mx = fmaxf(mx, lg[e]); }
            float sum = 0.f;
#pragma unroll
            for (int e = 0; e < E_NUM; ++e) { g[e] = __expf(lg[e] - mx); sum += g[e]; }
            float inv = 1.f / sum;
#pragma unroll
            for (int e = 0; e < E_NUM; ++e) g[e] *= inv;
            int e1 = 0; float v1 = g[0];
#pragma unroll
            for (int e = 1; e < E_NUM; ++e) if (g[e] > v1) { v1 = g[e]; e1 = e; }
            int e2 = -1; float v2 = -1.f;
#pragma unroll
            for (int e = 0; e < E_NUM; ++e) if (e != e1 && g[e] > v2) { v2 = g[e]; e2 = e; }
            topk_idx[t * 2 + 0] = e1; topk_idx[t * 2 + 1] = e2;
            topk_w[t * 2 + 0] = v1;   topk_w[t * 2 + 1] = v2;
#pragma unroll
            for (int e = 0; e < E_NUM; ++e) atomicAdd(&blk_sg[e], g[e]);
            atomicAdd(&blk_cnt[e1], 1); atomicAdd(&blk_cnt[e2], 1);
        }
    }
    __syncthreads();
    if (threadIdx.x < E_NUM) {
        atomicAdd((float*)(meta + MI_SUMG) + threadIdx.x, blk_sg[threadIdx.x]);
        atomicAdd(meta + MI_COUNT + threadIdx.x, blk_cnt[threadIdx.x]);
    }
}

// ---------------- scan: offsets (128-padded), rowtile table, aux loss ----------------
__global__ __launch_bounds__(256) void scan_kernel(int* __restrict__ meta, float* __restrict__ out_aux)
{
    __shared__ int offs[E_NUM + 1];
    const int tid = threadIdx.x;
    if (tid == 0) {
        int off = 0;
        for (int e = 0; e < E_NUM; ++e) {
            meta[MI_OFF + e] = off;
            offs[e] = off;
            int cnt = meta[MI_COUNT + e];
            off += ((cnt + 127) >> 7) << 7;
        }
        meta[MI_OFF + E_NUM] = off;
        offs[E_NUM] = off;
        meta[MI_TOTAL] = off >> 7;
        const float* sg = (const float*)(meta + MI_SUMG);
        float aux = 0.f;
        for (int e = 0; e < E_NUM; ++e)
            aux += (sg[e] / (float)N_TOK) * ((float)meta[MI_COUNT + e] / (float)N_TOK);
        out_aux[0] = aux * (float)E_NUM / (float)N_TOK;
    }
    __syncthreads();
    const int total = offs[E_NUM] >> 7;
    for (int rt = tid; rt < total; rt += 256) {
        int row = rt << 7, e = 0;
#pragma unroll
        for (int k = 1; k < E_NUM; ++k) if (row >= offs[k]) e = k;
        meta[MI_RTE + rt] = e;
    }
}

// ---------------- fill compacted slot lists (+ per-token slot map) ----------------
__global__ __launch_bounds__(256) void fill_kernel(
    const int* __restrict__ topk_idx, const float* __restrict__ topk_w,
    int* __restrict__ meta, int* __restrict__ slot_token, float* __restrict__ slot_weight,
    int* __restrict__ slot_of)
{
    int t = blockIdx.x * 256 + threadIdx.x;
#pragma unroll
    for (int k = 0; k < 2; ++k) {
        int e = topk_idx[t * 2 + k];
        int p = atomicAdd(meta + MI_CURSOR + e, 1);
        int slot = meta[MI_OFF + e] + p;
        slot_token[slot] = t;
        slot_weight[slot] = topk_w[t * 2 + k];
        slot_of[t * 2 + k] = slot;
    }
}

// =====================================================================
// m97-proportion GEMM: 128x128 tile, BK=64, 256 threads (4 waves, 2x2
// grid of 64x64 wave tiles), SINGLE-buffered 32 KiB LDS.
// __launch_bounds__(256,4): 4 waves/EU -> 4 blocks/CU, VGPR budget 128
// (acc[4][4]=64 VGPRs fits; (256,5) capped at ~102 and SPILLED the
// accumulator -> R11's 2.7x regression. Do not raise this again.)
// SWZ: chunked XCD swizzle (T1) — ON for gemm2 (proven win), OFF for
// gemm1 (natural round-robin gives best B-reuse; chunked tripled FETCH).
// Split-K: kp writes f16 partials at kp*out_kp_stride.
// =====================================================================

template<int KD, int NCOLS, int KSPLIT, bool GATHER, bool GELU, bool BIAS, bool SWZ>
__global__ __launch_bounds__(256, 4) void gemm128_kernel(
    const f16* __restrict__ A, const f16* __restrict__ Bw,
    const float* __restrict__ bias, const int* __restrict__ slot_token,
    const int* __restrict__ meta, f16* __restrict__ Out, size_t out_kp_stride)
{
    constexpr int KLOC = KD / KSPLIT;
    constexpr int NT = KLOC / 64;
    __shared__ __align__(16) f16 As[128 * 64];   // 16 KiB
    __shared__ __align__(16) f16 Bs[128 * 64];   // 16 KiB

    int nt, rt, kp;
    if (SWZ) {
        const int gx = gridDim.x, gy = gridDim.y;
        const int nwg = gx * gy * gridDim.z;
        const int flat = (blockIdx.z * gy + blockIdx.y) * gx + blockIdx.x;
        const int swz = (flat & 7) * (nwg >> 3) + (flat >> 3);
        nt = swz % gx;
        const int tmp = swz / gx;
        rt = tmp % gy;
        kp = tmp / gy;
    } else {
        nt = blockIdx.x; rt = blockIdx.y; kp = blockIdx.z;
    }

    if (rt >= meta[MI_TOTAL]) return;
    const int e  = meta[MI_RTE + rt];
    const int kbase = kp * KLOC;

    const int tid = threadIdx.x;
    const int w = tid >> 6, l = tid & 63;
    const int wr2 = w >> 1, wc2 = w & 1;        // 2 (M) x 2 (N) waves, 64x64 each
    const int fr = l & 15, fq = l >> 4;

    const int srow = tid >> 3;                  // 0..31
    const int kcs  = (tid & 7) ^ (srow & 7);    // pre-swizzled source chunk

    const f16* asrc[4]; const f16* bsrc[4];
#pragma unroll
    for (int i = 0; i < 4; ++i) {
        int r = i * 32 + srow;                  // row within 128-tile
        int ar;
        if (GATHER) ar = slot_token[rt * 128 + r];
        else        ar = rt * 128 + r;
        asrc[i] = A + (size_t)ar * KD + kbase + kcs * 8;
        bsrc[i] = Bw + ((size_t)e * NCOLS + (size_t)nt * 128 + r) * KD + kbase + kcs * 8;
    }

    const int rA  = wr2 * 64 + fr;
    const int rB  = wc2 * 64 + fr;
    const int sw0 = ( fq      ^ (fr & 7)) * 8;  // swizzled chunk offsets (f16 units), kk=0
    const int sw1 = ((4 + fq) ^ (fr & 7)) * 8;  // kk=32

    floatx4 acc[4][4];
#pragma unroll
    for (int m = 0; m < 4; ++m)
#pragma unroll
        for (int n = 0; n < 4; ++n) acc[m][n] = (floatx4){0.f, 0.f, 0.f, 0.f};

    half8 af[4], bf[4];

#pragma unroll 2
    for (int t = 0; t < NT; ++t) {
        // stage tile t (single buffer)
#pragma unroll
        for (int i = 0; i < 4; ++i) {
            gld_lds16(asrc[i] + (size_t)t * 64, &As[i * 2048 + tid * 8]);
            gld_lds16(bsrc[i] + (size_t)t * 64, &Bs[i * 2048 + tid * 8]);
        }
        asm volatile("s_waitcnt vmcnt(0)" ::: "memory");
        __builtin_amdgcn_s_barrier();
        // compute: 2 kk-halves x (8 ds_read + 16 MFMA)
#pragma unroll
        for (int kk2 = 0; kk2 < 2; ++kk2) {
            const int sw = kk2 ? sw1 : sw0;
#pragma unroll
            for (int mj = 0; mj < 4; ++mj)
                af[mj] = *(const half8*)&As[(size_t)(rA + mj * 16) * 64 + sw];
#pragma unroll
            for (int nj = 0; nj < 4; ++nj)
                bf[nj] = *(const half8*)&Bs[(size_t)(rB + nj * 16) * 64 + sw];
#pragma unroll
            for (int mj = 0; mj < 4; ++mj)
#pragma unroll
                for (int nj = 0; nj < 4; ++nj)
                    acc[mj][nj] = __builtin_amdgcn_mfma_f32_16x16x32_f16(
                        af[mj], bf[nj], acc[mj][nj], 0, 0, 0);
        }
        __builtin_amdgcn_s_barrier();   // all reads consumed before next stage
    }

    // ---- epilogue: 64 outputs/thread ----
    f16* Op = Out + (size_t)kp * out_kp_stride;
    const int orow0 = rt * 128 + wr2 * 64;
    const int ocol0 = nt * 128 + wc2 * 64;
#pragma unroll
    for (int mj = 0; mj < 4; ++mj) {
#pragma unroll
        for (int nj = 0; nj < 4; ++nj) {
            const int col = ocol0 + nj * 16 + fr;
            float bs = 0.f;
            if (BIAS) bs = bias[(size_t)e * NCOLS + col];
#pragma unroll
            for (int j = 0; j < 4; ++j) {
                const int row = orow0 + mj * 16 + fq * 4 + j;
                float v = acc[mj][nj][j] + bs;
                if (GELU) v = gelu_f(v);
                Op[(size_t)row * NCOLS + col] = (f16)v;
            }
        }
    }
}

// ------- combine: out[t] = w0*(P0[s0]+P1[s0]+b2[e0]) + w1*(P0[s1]+P1[s1]+b2[e1]) -------
__global__ __launch_bounds__(256) void combine_kernel(
    const f16* __restrict__ P, const int* __restrict__ slot_of,
    const int* __restrict__ topk_idx, const float* __restrict__ topk_w,
    const float* __restrict__ b2, float* __restrict__ out)
{
    const int t = blockIdx.x;
    const int c = threadIdx.x;          // 256 threads x 4 cols
    const size_t PS = (size_t)MAX_SLOTS * D_DIM;
    const int s0 = slot_of[t * 2], s1 = slot_of[t * 2 + 1];
    const int e0 = topk_idx[t * 2], e1 = topk_idx[t * 2 + 1];
    const float w0 = topk_w[t * 2], w1 = topk_w[t * 2 + 1];
    half4 a0 = *(const half4*)(P + (size_t)s0 * D_DIM + c * 4);
    half4 a1 = *(const half4*)(P + PS + (size_t)s0 * D_DIM + c * 4);
    half4 c0 = *(const half4*)(P + (size_t)s1 * D_DIM + c * 4);
    half4 c1 = *(const half4*)(P + PS + (size_t)s1 * D_DIM + c * 4);
    float4 bb0 = *(const float4*)(b2 + (size_t)e0 * D_DIM + c * 4);
    float4 bb1 = *(const float4*)(b2 + (size_t)e1 * D_DIM + c * 4);
    float4 o;
    o.x = w0 * ((float)a0[0] + (float)a1[0] + bb0.x) + w1 * ((float)c0[0] + (float)c1[0] + bb1.x);
    o.y = w0 * ((float)a0[1] + (float)a1[1] + bb0.y) + w1 * ((float)c0[1] + (float)c1[1] + bb1.y);
    o.z = w0 * ((float)a0[2] + (float)a1[2] + bb0.z) + w1 * ((float)c0[2] + (float)c1[2] + bb1.z);
    o.w = w0 * ((float)a0[3] + (float)a1[3] + bb0.w) + w1 * ((float)c0[3] + (float)c1[3] + bb1.w);
    *(float4*)(out + (size_t)t * D_DIM + c * 4) = o;
}

extern "C" void kernel_launch(void* const* d_in, const int* in_sizes, int n_in,
                              void* d_out, int out_size, void* d_ws, size_t ws_size,
                              hipStream_t stream) {
    const float* x  = (const float*)d_in[0];
    const float* Wr = (const float*)d_in[1];
    const float* br = (const float*)d_in[2];
    const float* W1 = (const float*)d_in[3];
    const float* b1 = (const float*)d_in[4];
    const float* W2 = (const float*)d_in[5];
    const float* b2 = (const float*)d_in[6];
    float* out = (float*)d_out;

    char* ws = (char*)d_ws;
    const size_t SZ_XH  = (size_t)N_TOK * D_DIM * 2;          // 16 MiB
    const size_t SZ_W1T = (size_t)E_NUM * DF_DIM * D_DIM * 2; // 64 MiB
    const size_t SZ_W2T = SZ_W1T;
    const size_t SZ_H   = (size_t)MAX_SLOTS * DF_DIM * 2;     // 136 MiB

    f16* xh  = (f16*)(ws);
    f16* W1t = (f16*)(ws + SZ_XH);
    f16* W2t = (f16*)(ws + SZ_XH + SZ_W1T);
    f16* H   = (f16*)(ws + SZ_XH + SZ_W1T + SZ_W2T);
    // P (2 split-K partials, 34 MiB each) aliases [xh | W1t] (80 MiB) — dead after gemm1.
    f16* P   = (f16*)ws;
    char* p  = ws + SZ_XH + SZ_W1T + SZ_W2T + SZ_H;
    int*   topk_idx    = (int*)p;    p += (size_t)N_TOK * 2 * 4;
    float* topk_w      = (float*)p;  p += (size_t)N_TOK * 2 * 4;
    int*   slot_token  = (int*)p;    p += (size_t)MAX_SLOTS * 4;
    float* slot_weight = (float*)p;  p += (size_t)MAX_SLOTS * 4;
    int*   slot_of     = (int*)p;    p += (size_t)N_TOK * 2 * 4;
    int*   meta        = (int*)p;

    // per-call init: zero slot lists (pad slots -> token 0 / weight 0) + slot_of + meta
    hipMemsetAsync(slot_token, 0, (size_t)MAX_SLOTS * 8 + (size_t)N_TOK * 2 * 4 + 1024, stream);

    // prep: transposes + router fused into one launch (16896 blocks)
    prep_kernel<<<16896, 256, 0, stream>>>(
        W1, W2, W1t, W2t, x, Wr, br, topk_idx, topk_w, meta, xh);

    scan_kernel<<<1, 256, 0, stream>>>(meta, out + (size_t)N_TOK * D_DIM);
    fill_kernel<<<N_TOK / 256, 256, 0, stream>>>(topk_idx, topk_w, meta, slot_token, slot_weight, slot_of);

    // GEMM1 (m97-style 128-tile, natural order): H = gelu(gather(xh) @ W1t + b1)
    gemm128_kernel<D_DIM, DF_DIM, 1, true, true, true, false>
        <<<dim3(DF_DIM / 128, MAX_RT, 1), 256, 0, stream>>>(
        xh, W1t, b1, slot_token, meta, H, 0);

    // GEMM2 (m97-style 128-tile, XCD swizzle, split-K=2): P[kp] = H @ W2t
    gemm128_kernel<DF_DIM, D_DIM, 2, false, false, false, true>
        <<<dim3(D_DIM / 128, MAX_RT, 2), 256, 0, stream>>>(
        H, W2t, nullptr, slot_token, meta, P, (size_t)MAX_SLOTS * D_DIM);

    combine_kernel<<<N_TOK, 256, 0, stream>>>(P, slot_of, topk_idx, topk_w, b2, out);

    (void)in_sizes; (void)n_in; (void)ws_size;
}

// Round 14
// 539.620 us; speedup vs baseline: 2.8901x; 1.0234x over previous
//
#include <hip/hip_runtime.h>
#include <hip/hip_bf16.h>
#include <hip/hip_fp16.h>

typedef _Float16 f16;
typedef _Float16 half8 __attribute__((ext_vector_type(8)));
typedef _Float16 half4 __attribute__((ext_vector_type(4)));
typedef float   floatx4 __attribute__((ext_vector_type(4)));

#define N_TOK   8192
#define D_DIM   1024
#define E_NUM   8
#define DF_DIM  4096
#define MAX_SLOTS 17408   // 16384 + 8*128 padding
#define MAX_RT    136     // MAX_SLOTS / 128

// meta layout (int32 indices)
#define MI_COUNT  0    // [8]
#define MI_CURSOR 8    // [8]
#define MI_OFF    16   // [9]
#define MI_TOTAL  25   // [1]  (# of 128-row tiles)
#define MI_RTE    26   // [136]
#define MI_SUMG   168  // [8] floats

__device__ __forceinline__ void gld_lds16(const void* g, void* l) {
    __builtin_amdgcn_global_load_lds(
        (__attribute__((address_space(1))) const void*)g,
        (__attribute__((address_space(3))) void*)l, 16, 0, 0);
}

// tanh-form GELU: max |err| vs erf-GELU ~3e-4 in h -> ~1e-3 in out (thr 0.026)
__device__ __forceinline__ float gelu_f(float v) {
    float u = 0.7978845608028654f * v * (1.0f + 0.044715f * v * v);
    float t = __expf(-2.0f * fabsf(u));
    float th = (1.0f - t) / (1.0f + t);
    th = (u >= 0.f) ? th : -th;
    return 0.5f * v * (1.0f + th);
}

// ---- 64x64 transpose+convert tile helper (f32 [R][C] -> f16 [C][R]) ----
__device__ __forceinline__ void transpose_tile(
    const float* __restrict__ src, f16* __restrict__ dst, int R, int C,
    int rb, int cb, float* tile /* [64*65] LDS */)
{
    const int tid = threadIdx.x;
#pragma unroll
    for (int j = 0; j < 4; ++j) {
        int lin = j * 1024 + tid * 4;
        int r = lin >> 6, c = lin & 63;
        float4 v = *(const float4*)(src + (size_t)(rb + r) * C + (cb + c));
        tile[r * 65 + c + 0] = v.x; tile[r * 65 + c + 1] = v.y;
        tile[r * 65 + c + 2] = v.z; tile[r * 65 + c + 3] = v.w;
    }
    __syncthreads();
#pragma unroll
    for (int j = 0; j < 4; ++j) {
        int lin = j * 1024 + tid * 4;
        int c = lin >> 6, r = lin & 63;
        half4 o = { (f16)tile[(r + 0) * 65 + c], (f16)tile[(r + 1) * 65 + c],
                    (f16)tile[(r + 2) * 65 + c], (f16)tile[(r + 3) * 65 + c] };
        *(half4*)(dst + (size_t)(cb + c) * R + (rb + r)) = o;
    }
}

// =====================================================================
// prep_kernel: transpose W1 (blocks [0,8192)) + router (blocks [8192,8704))
// W2's transpose is fused into gemm1's launch (tail blocks) since its
// only consumer is gemm2.
// =====================================================================
__global__ __launch_bounds__(256) void prep_kernel(
    const float* __restrict__ W1, f16* __restrict__ W1t,
    const float* __restrict__ x, const float* __restrict__ Wr,
    const float* __restrict__ br,
    int* __restrict__ topk_idx, float* __restrict__ topk_w,
    int* __restrict__ meta, f16* __restrict__ xh)
{
    __shared__ float tile[64 * 65];
    __shared__ float blk_sg[E_NUM];
    __shared__ int   blk_cnt[E_NUM];

    const int bid = blockIdx.x;
    if (bid < 8192) {
        // ---- transpose W1: R=D, C=DF, grid (64, 16, 8) flattened ----
        const int cx = bid & 63, ry = (bid >> 6) & 15, ez = bid >> 10;
        transpose_tile(W1 + (size_t)ez * D_DIM * DF_DIM,
                       W1t + (size_t)ez * D_DIM * DF_DIM,
                       D_DIM, DF_DIM, ry * 64, cx * 64, tile);
        return;
    }

    // ---- router (fused x->f16 convert): 512 blocks x 16 tokens ----
    const int rb = bid - 8192;
    const int w = threadIdx.x >> 6, l = threadIdx.x & 63;
    if (threadIdx.x < E_NUM) { blk_sg[threadIdx.x] = 0.f; blk_cnt[threadIdx.x] = 0; }
    __syncthreads();

    for (int it = 0; it < 4; ++it) {
        const int t = rb * 16 + w * 4 + it;
        const float* xr = x + (size_t)t * D_DIM + l * 16;
        float acc[E_NUM] = {0.f,0.f,0.f,0.f,0.f,0.f,0.f,0.f};
        f16 hx[16];
#pragma unroll
        for (int i = 0; i < 16; i += 4) {
            float4 xv = *(const float4*)(xr + i);
            const float xs[4] = {xv.x, xv.y, xv.z, xv.w};
#pragma unroll
            for (int jj = 0; jj < 4; ++jj) {
                hx[i + jj] = (f16)xs[jj];
                int d = l * 16 + i + jj;
                float4 w0 = *(const float4*)(Wr + (size_t)d * 8);
                float4 w1 = *(const float4*)(Wr + (size_t)d * 8 + 4);
                acc[0] += xs[jj] * w0.x; acc[1] += xs[jj] * w0.y;
                acc[2] += xs[jj] * w0.z; acc[3] += xs[jj] * w0.w;
                acc[4] += xs[jj] * w1.x; acc[5] += xs[jj] * w1.y;
                acc[6] += xs[jj] * w1.z; acc[7] += xs[jj] * w1.w;
            }
        }
        // fused convert: write this row segment as f16
        f16* xo = xh + (size_t)t * D_DIM + l * 16;
        *(half8*)(xo)     = *(const half8*)&hx[0];
        *(half8*)(xo + 8) = *(const half8*)&hx[8];
#pragma unroll
        for (int e = 0; e < E_NUM; ++e) {
#pragma unroll
            for (int off = 32; off > 0; off >>= 1)
                acc[e] += __shfl_down(acc[e], off);
        }
        if (l == 0) {
            float lg[E_NUM], g[E_NUM];
            float mx = -1e30f;
#pragma unroll
            for (int e = 0; e < E_NUM; ++e) { lg[e] = acc[e] + br[e]; mx = fmaxf(mx, lg[e]); }
            float sum = 0.f;
#pragma unroll
            for (int e = 0; e < E_NUM; ++e) { g[e] = __expf(lg[e] - mx); sum += g[e]; }
            float inv = 1.f / sum;
#pragma unroll
            for (int e = 0; e < E_NUM; ++e) g[e] *= inv;
            int e1 = 0; float v1 = g[0];
#pragma unroll
            for (int e = 1; e < E_NUM; ++e) if (g[e] > v1) { v1 = g[e]; e1 = e; }
            int e2 = -1; float v2 = -1.f;
#pragma unroll
            for (int e = 0; e < E_NUM; ++e) if (e != e1 && g[e] > v2) { v2 = g[e]; e2 = e; }
            topk_idx[t * 2 + 0] = e1; topk_idx[t * 2 + 1] = e2;
            topk_w[t * 2 + 0] = v1;   topk_w[t * 2 + 1] = v2;
#pragma unroll
            for (int e = 0; e < E_NUM; ++e) atomicAdd(&blk_sg[e], g[e]);
            atomicAdd(&blk_cnt[e1], 1); atomicAdd(&blk_cnt[e2], 1);
        }
    }
    __syncthreads();
    if (threadIdx.x < E_NUM) {
        atomicAdd((float*)(meta + MI_SUMG) + threadIdx.x, blk_sg[threadIdx.x]);
        atomicAdd(meta + MI_COUNT + threadIdx.x, blk_cnt[threadIdx.x]);
    }
}

// ---------------- scan: offsets (128-padded), rowtile table, aux loss ----------------
__global__ __launch_bounds__(256) void scan_kernel(int* __restrict__ meta, float* __restrict__ out_aux)
{
    __shared__ int offs[E_NUM + 1];
    const int tid = threadIdx.x;
    if (tid == 0) {
        int off = 0;
        for (int e = 0; e < E_NUM; ++e) {
            meta[MI_OFF + e] = off;
            offs[e] = off;
            int cnt = meta[MI_COUNT + e];
            off += ((cnt + 127) >> 7) << 7;
        }
        meta[MI_OFF + E_NUM] = off;
        offs[E_NUM] = off;
        meta[MI_TOTAL] = off >> 7;
        const float* sg = (const float*)(meta + MI_SUMG);
        float aux = 0.f;
        for (int e = 0; e < E_NUM; ++e)
            aux += (sg[e] / (float)N_TOK) * ((float)meta[MI_COUNT + e] / (float)N_TOK);
        out_aux[0] = aux * (float)E_NUM / (float)N_TOK;
    }
    __syncthreads();
    const int total = offs[E_NUM] >> 7;
    for (int rt = tid; rt < total; rt += 256) {
        int row = rt << 7, e = 0;
#pragma unroll
        for (int k = 1; k < E_NUM; ++k) if (row >= offs[k]) e = k;
        meta[MI_RTE + rt] = e;
    }
}

// ---------------- fill compacted slot lists (+ per-token slot map) ----------------
__global__ __launch_bounds__(256) void fill_kernel(
    const int* __restrict__ topk_idx, const float* __restrict__ topk_w,
    int* __restrict__ meta, int* __restrict__ slot_token, float* __restrict__ slot_weight,
    int* __restrict__ slot_of)
{
    int t = blockIdx.x * 256 + threadIdx.x;
#pragma unroll
    for (int k = 0; k < 2; ++k) {
        int e = topk_idx[t * 2 + k];
        int p = atomicAdd(meta + MI_CURSOR + e, 1);
        int slot = meta[MI_OFF + e] + p;
        slot_token[slot] = t;
        slot_weight[slot] = topk_w[t * 2 + k];
        slot_of[t * 2 + k] = slot;
    }
}

// =====================================================================
// m97-proportion GEMM: 128x128 tile, BK=64, 256 threads (4 waves, 2x2
// grid of 64x64 wave tiles), SINGLE-buffered 32 KiB LDS (raw overlay).
// __launch_bounds__(256,4): VGPR budget 128 — acc=64 fits; (256,5)
// spilled (R11, 2.7x regression). Do not raise.
// SWZ: chunked XCD swizzle — ON for gemm2, OFF for gemm1.
// FUSET: blocks with blockIdx.y >= MAX_RT run the W2 transpose
// (8192 tail blocks; dispatch order x-fastest => all gemm blocks first;
// W2t's only consumer is gemm2, launched after).
// =====================================================================

template<int KD, int NCOLS, int KSPLIT, bool GATHER, bool GELU, bool BIAS, bool SWZ, bool FUSET>
__global__ __launch_bounds__(256, 4) void gemm128_kernel(
    const f16* __restrict__ A, const f16* __restrict__ Bw,
    const float* __restrict__ bias, const int* __restrict__ slot_token,
    const int* __restrict__ meta, f16* __restrict__ Out, size_t out_kp_stride,
    const float* __restrict__ Tsrc, f16* __restrict__ Tdst)
{
    constexpr int KLOC = KD / KSPLIT;
    constexpr int NT = KLOC / 64;
    __shared__ __align__(16) char smem_raw[32768];
    f16* As = (f16*)smem_raw;             // 16 KiB
    f16* Bs = (f16*)(smem_raw + 16384);   // 16 KiB

    if (FUSET && blockIdx.y >= MAX_RT) {
        // ---- fused W2 transpose tail: R=DF, C=D, 8192 blocks ----
        const int id = (blockIdx.y - MAX_RT) * gridDim.x + blockIdx.x;
        const int cx = id & 15, ry = (id >> 4) & 63, ez = id >> 10;
        transpose_tile(Tsrc + (size_t)ez * D_DIM * DF_DIM,
                       Tdst + (size_t)ez * D_DIM * DF_DIM,
                       DF_DIM, D_DIM, ry * 64, cx * 64, (float*)smem_raw);
        return;
    }

    int nt, rt, kp;
    if (SWZ) {
        const int gx = gridDim.x, gy = gridDim.y;
        const int nwg = gx * gy * gridDim.z;
        const int flat = (blockIdx.z * gy + blockIdx.y) * gx + blockIdx.x;
        const int swz = (flat & 7) * (nwg >> 3) + (flat >> 3);
        nt = swz % gx;
        const int tmp = swz / gx;
        rt = tmp % gy;
        kp = tmp / gy;
    } else {
        nt = blockIdx.x; rt = blockIdx.y; kp = blockIdx.z;
    }

    if (rt >= meta[MI_TOTAL]) return;
    const int e  = meta[MI_RTE + rt];
    const int kbase = kp * KLOC;

    const int tid = threadIdx.x;
    const int w = tid >> 6, l = tid & 63;
    const int wr2 = w >> 1, wc2 = w & 1;        // 2 (M) x 2 (N) waves, 64x64 each
    const int fr = l & 15, fq = l >> 4;

    const int srow = tid >> 3;                  // 0..31
    const int kcs  = (tid & 7) ^ (srow & 7);    // pre-swizzled source chunk

    const f16* asrc[4]; const f16* bsrc[4];
#pragma unroll
    for (int i = 0; i < 4; ++i) {
        int r = i * 32 + srow;                  // row within 128-tile
        int ar;
        if (GATHER) ar = slot_token[rt * 128 + r];
        else        ar = rt * 128 + r;
        asrc[i] = A + (size_t)ar * KD + kbase + kcs * 8;
        bsrc[i] = Bw + ((size_t)e * NCOLS + (size_t)nt * 128 + r) * KD + kbase + kcs * 8;
    }

    const int rA  = wr2 * 64 + fr;
    const int rB  = wc2 * 64 + fr;
    const int sw0 = ( fq      ^ (fr & 7)) * 8;  // swizzled chunk offsets (f16 units), kk=0
    const int sw1 = ((4 + fq) ^ (fr & 7)) * 8;  // kk=32

    floatx4 acc[4][4];
#pragma unroll
    for (int m = 0; m < 4; ++m)
#pragma unroll
        for (int n = 0; n < 4; ++n) acc[m][n] = (floatx4){0.f, 0.f, 0.f, 0.f};

    half8 af[4], bf[4];

#pragma unroll 2
    for (int t = 0; t < NT; ++t) {
        // stage tile t (single buffer)
#pragma unroll
        for (int i = 0; i < 4; ++i) {
            gld_lds16(asrc[i] + (size_t)t * 64, &As[i * 2048 + tid * 8]);
            gld_lds16(bsrc[i] + (size_t)t * 64, &Bs[i * 2048 + tid * 8]);
        }
        asm volatile("s_waitcnt vmcnt(0)" ::: "memory");
        __builtin_amdgcn_s_barrier();
        // compute: 2 kk-halves x (8 ds_read + 16 MFMA)
#pragma unroll
        for (int kk2 = 0; kk2 < 2; ++kk2) {
            const int sw = kk2 ? sw1 : sw0;
#pragma unroll
            for (int mj = 0; mj < 4; ++mj)
                af[mj] = *(const half8*)&As[(size_t)(rA + mj * 16) * 64 + sw];
#pragma unroll
            for (int nj = 0; nj < 4; ++nj)
                bf[nj] = *(const half8*)&Bs[(size_t)(rB + nj * 16) * 64 + sw];
#pragma unroll
            for (int mj = 0; mj < 4; ++mj)
#pragma unroll
                for (int nj = 0; nj < 4; ++nj)
                    acc[mj][nj] = __builtin_amdgcn_mfma_f32_16x16x32_f16(
                        af[mj], bf[nj], acc[mj][nj], 0, 0, 0);
        }
        __builtin_amdgcn_s_barrier();   // all reads consumed before next stage
    }

    // ---- epilogue: 64 outputs/thread ----
    f16* Op = Out + (size_t)kp * out_kp_stride;
    const int orow0 = rt * 128 + wr2 * 64;
    const int ocol0 = nt * 128 + wc2 * 64;
#pragma unroll
    for (int mj = 0; mj < 4; ++mj) {
#pragma unroll
        for (int nj = 0; nj < 4; ++nj) {
            const int col = ocol0 + nj * 16 + fr;
            float bs = 0.f;
            if (BIAS) bs = bias[(size_t)e * NCOLS + col];
#pragma unroll
            for (int j = 0; j < 4; ++j) {
                const int row = orow0 + mj * 16 + fq * 4 + j;
                float v = acc[mj][nj][j] + bs;
                if (GELU) v = gelu_f(v);
                Op[(size_t)row * NCOLS + col] = (f16)v;
            }
        }
    }
}

// ------- combine: out[t] = w0*(P0[s0]+P1[s0]+b2[e0]) + w1*(P0[s1]+P1[s1]+b2[e1]) -------
__global__ __launch_bounds__(256) void combine_kernel(
    const f16* __restrict__ P, const int* __restrict__ slot_of,
    const int* __restrict__ topk_idx, const float* __restrict__ topk_w,
    const float* __restrict__ b2, float* __restrict__ out)
{
    const int t = blockIdx.x;
    const int c = threadIdx.x;          // 256 threads x 4 cols
    const size_t PS = (size_t)MAX_SLOTS * D_DIM;
    const int s0 = slot_of[t * 2], s1 = slot_of[t * 2 + 1];
    const int e0 = topk_idx[t * 2], e1 = topk_idx[t * 2 + 1];
    const float w0 = topk_w[t * 2], w1 = topk_w[t * 2 + 1];
    half4 a0 = *(const half4*)(P + (size_t)s0 * D_DIM + c * 4);
    half4 a1 = *(const half4*)(P + PS + (size_t)s0 * D_DIM + c * 4);
    half4 c0 = *(const half4*)(P + (size_t)s1 * D_DIM + c * 4);
    half4 c1 = *(const half4*)(P + PS + (size_t)s1 * D_DIM + c * 4);
    float4 bb0 = *(const float4*)(b2 + (size_t)e0 * D_DIM + c * 4);
    float4 bb1 = *(const float4*)(b2 + (size_t)e1 * D_DIM + c * 4);
    float4 o;
    o.x = w0 * ((float)a0[0] + (float)a1[0] + bb0.x) + w1 * ((float)c0[0] + (float)c1[0] + bb1.x);
    o.y = w0 * ((float)a0[1] + (float)a1[1] + bb0.y) + w1 * ((float)c0[1] + (float)c1[1] + bb1.y);
    o.z = w0 * ((float)a0[2] + (float)a1[2] + bb0.z) + w1 * ((float)c0[2] + (float)c1[2] + bb1.z);
    o.w = w0 * ((float)a0[3] + (float)a1[3] + bb0.w) + w1 * ((float)c0[3] + (float)c1[3] + bb1.w);
    *(float4*)(out + (size_t)t * D_DIM + c * 4) = o;
}

extern "C" void kernel_launch(void* const* d_in, const int* in_sizes, int n_in,
                              void* d_out, int out_size, void* d_ws, size_t ws_size,
                              hipStream_t stream) {
    const float* x  = (const float*)d_in[0];
    const float* Wr = (const float*)d_in[1];
    const float* br = (const float*)d_in[2];
    const float* W1 = (const float*)d_in[3];
    const float* b1 = (const float*)d_in[4];
    const float* W2 = (const float*)d_in[5];
    const float* b2 = (const float*)d_in[6];
    float* out = (float*)d_out;

    char* ws = (char*)d_ws;
    const size_t SZ_XH  = (size_t)N_TOK * D_DIM * 2;          // 16 MiB
    const size_t SZ_W1T = (size_t)E_NUM * DF_DIM * D_DIM * 2; // 64 MiB
    const size_t SZ_W2T = SZ_W1T;
    const size_t SZ_H   = (size_t)MAX_SLOTS * DF_DIM * 2;     // 136 MiB

    f16* xh  = (f16*)(ws);
    f16* W1t = (f16*)(ws + SZ_XH);
    f16* W2t = (f16*)(ws + SZ_XH + SZ_W1T);
    f16* H   = (f16*)(ws + SZ_XH + SZ_W1T + SZ_W2T);
    // P (2 split-K partials, 34 MiB each) aliases [xh | W1t] (80 MiB) — dead after gemm1.
    f16* P   = (f16*)ws;
    char* p  = ws + SZ_XH + SZ_W1T + SZ_W2T + SZ_H;
    int*   topk_idx    = (int*)p;    p += (size_t)N_TOK * 2 * 4;
    float* topk_w      = (float*)p;  p += (size_t)N_TOK * 2 * 4;
    int*   slot_token  = (int*)p;    p += (size_t)MAX_SLOTS * 4;
    float* slot_weight = (float*)p;  p += (size_t)MAX_SLOTS * 4;
    int*   slot_of     = (int*)p;    p += (size_t)N_TOK * 2 * 4;
    int*   meta        = (int*)p;

    // per-call init: zero slot lists (pad slots -> token 0 / weight 0) + slot_of + meta
    hipMemsetAsync(slot_token, 0, (size_t)MAX_SLOTS * 8 + (size_t)N_TOK * 2 * 4 + 1024, stream);

    // prep: W1 transpose + router (8704 blocks). W2 transpose rides in gemm1.
    prep_kernel<<<8704, 256, 0, stream>>>(
        W1, W1t, x, Wr, br, topk_idx, topk_w, meta, xh);

    scan_kernel<<<1, 256, 0, stream>>>(meta, out + (size_t)N_TOK * D_DIM);
    fill_kernel<<<N_TOK / 256, 256, 0, stream>>>(topk_idx, topk_w, meta, slot_token, slot_weight, slot_of);

    // GEMM1 + fused W2 transpose tail: H = gelu(gather(xh) @ W1t + b1)
    // grid y: 136 gemm rows + 256 transpose rows (8192 blocks of 32)
    gemm128_kernel<D_DIM, DF_DIM, 1, true, true, true, false, true>
        <<<dim3(DF_DIM / 128, MAX_RT + 256, 1), 256, 0, stream>>>(
        xh, W1t, b1, slot_token, meta, H, 0, W2, W2t);

    // GEMM2 (XCD swizzle, split-K=2): P[kp] = H @ W2t
    gemm128_kernel<DF_DIM, D_DIM, 2, false, false, false, true, false>
        <<<dim3(D_DIM / 128, MAX_RT, 2), 256, 0, stream>>>(
        H, W2t, nullptr, slot_token, meta, P, (size_t)MAX_SLOTS * D_DIM, nullptr, nullptr);

    combine_kernel<<<N_TOK, 256, 0, stream>>>(P, slot_of, topk_idx, topk_w, b2, out);

    (void)in_sizes; (void)n_in; (void)ws_size;
}

// Round 15
// 514.716 us; speedup vs baseline: 3.0300x; 1.0484x over previous
//
#include <hip/hip_runtime.h>
#include <hip/hip_bf16.h>
#include <hip/hip_fp16.h>

typedef _Float16 f16;
typedef _Float16 half8 __attribute__((ext_vector_type(8)));
typedef _Float16 half4 __attribute__((ext_vector_type(4)));
typedef float   floatx4 __attribute__((ext_vector_type(4)));

#define N_TOK   8192
#define D_DIM   1024
#define E_NUM   8
#define DF_DIM  4096
#define MAX_SLOTS 17408   // 16384 + 8*128 padding
#define MAX_RT    136     // MAX_SLOTS / 128

// meta layout (int32 indices)
#define MI_COUNT  0    // [8]
#define MI_CURSOR 8    // [8]
#define MI_OFF    16   // [9]
#define MI_TOTAL  25   // [1]  (# of 128-row tiles)
#define MI_RTE    26   // [136]
#define MI_SUMG   168  // [8] floats

__device__ __forceinline__ void gld_lds16(const void* g, void* l) {
    __builtin_amdgcn_global_load_lds(
        (__attribute__((address_space(1))) const void*)g,
        (__attribute__((address_space(3))) void*)l, 16, 0, 0);
}

// tanh-form GELU: max |err| vs erf-GELU ~3e-4 in h -> ~1e-3 in out (thr 0.026)
__device__ __forceinline__ float gelu_f(float v) {
    float u = 0.7978845608028654f * v * (1.0f + 0.044715f * v * v);
    float t = __expf(-2.0f * fabsf(u));
    float th = (1.0f - t) / (1.0f + t);
    th = (u >= 0.f) ? th : -th;
    return 0.5f * v * (1.0f + th);
}

// ---- 64x64 transpose+convert tile helper (f32 [R][C] -> f16 [C][R]) ----
__device__ __forceinline__ void transpose_tile(
    const float* __restrict__ src, f16* __restrict__ dst, int R, int C,
    int rb, int cb, float* tile /* [64*65] LDS */)
{
    const int tid = threadIdx.x;
#pragma unroll
    for (int j = 0; j < 4; ++j) {
        int lin = j * 1024 + tid * 4;
        int r = lin >> 6, c = lin & 63;
        float4 v = *(const float4*)(src + (size_t)(rb + r) * C + (cb + c));
        tile[r * 65 + c + 0] = v.x; tile[r * 65 + c + 1] = v.y;
        tile[r * 65 + c + 2] = v.z; tile[r * 65 + c + 3] = v.w;
    }
    __syncthreads();
#pragma unroll
    for (int j = 0; j < 4; ++j) {
        int lin = j * 1024 + tid * 4;
        int c = lin >> 6, r = lin & 63;
        half4 o = { (f16)tile[(r + 0) * 65 + c], (f16)tile[(r + 1) * 65 + c],
                    (f16)tile[(r + 2) * 65 + c], (f16)tile[(r + 3) * 65 + c] };
        *(half4*)(dst + (size_t)(cb + c) * R + (rb + r)) = o;
    }
}

// =====================================================================
// prep_kernel: transpose W1 (blocks [0,8192)) + router (blocks [8192,8704))
// W2's transpose is fused into gemm1's launch (tail blocks).
// =====================================================================
__global__ __launch_bounds__(256) void prep_kernel(
    const float* __restrict__ W1, f16* __restrict__ W1t,
    const float* __restrict__ x, const float* __restrict__ Wr,
    const float* __restrict__ br,
    int* __restrict__ topk_idx, float* __restrict__ topk_w,
    int* __restrict__ meta, f16* __restrict__ xh)
{
    __shared__ float tile[64 * 65];
    __shared__ float blk_sg[E_NUM];
    __shared__ int   blk_cnt[E_NUM];

    const int bid = blockIdx.x;
    if (bid < 8192) {
        // ---- transpose W1: R=D, C=DF, grid (64, 16, 8) flattened ----
        const int cx = bid & 63, ry = (bid >> 6) & 15, ez = bid >> 10;
        transpose_tile(W1 + (size_t)ez * D_DIM * DF_DIM,
                       W1t + (size_t)ez * D_DIM * DF_DIM,
                       D_DIM, DF_DIM, ry * 64, cx * 64, tile);
        return;
    }

    // ---- router (fused x->f16 convert): 512 blocks x 16 tokens ----
    const int rb = bid - 8192;
    const int w = threadIdx.x >> 6, l = threadIdx.x & 63;
    if (threadIdx.x < E_NUM) { blk_sg[threadIdx.x] = 0.f; blk_cnt[threadIdx.x] = 0; }
    __syncthreads();

    for (int it = 0; it < 4; ++it) {
        const int t = rb * 16 + w * 4 + it;
        const float* xr = x + (size_t)t * D_DIM + l * 16;
        float acc[E_NUM] = {0.f,0.f,0.f,0.f,0.f,0.f,0.f,0.f};
        f16 hx[16];
#pragma unroll
        for (int i = 0; i < 16; i += 4) {
            float4 xv = *(const float4*)(xr + i);
            const float xs[4] = {xv.x, xv.y, xv.z, xv.w};
#pragma unroll
            for (int jj = 0; jj < 4; ++jj) {
                hx[i + jj] = (f16)xs[jj];
                int d = l * 16 + i + jj;
                float4 w0 = *(const float4*)(Wr + (size_t)d * 8);
                float4 w1 = *(const float4*)(Wr + (size_t)d * 8 + 4);
                acc[0] += xs[jj] * w0.x; acc[1] += xs[jj] * w0.y;
                acc[2] += xs[jj] * w0.z; acc[3] += xs[jj] * w0.w;
                acc[4] += xs[jj] * w1.x; acc[5] += xs[jj] * w1.y;
                acc[6] += xs[jj] * w1.z; acc[7] += xs[jj] * w1.w;
            }
        }
        // fused convert: write this row segment as f16
        f16* xo = xh + (size_t)t * D_DIM + l * 16;
        *(half8*)(xo)     = *(const half8*)&hx[0];
        *(half8*)(xo + 8) = *(const half8*)&hx[8];
#pragma unroll
        for (int e = 0; e < E_NUM; ++e) {
#pragma unroll
            for (int off = 32; off > 0; off >>= 1)
                acc[e] += __shfl_down(acc[e], off);
        }
        if (l == 0) {
            float lg[E_NUM], g[E_NUM];
            float mx = -1e30f;
#pragma unroll
            for (int e = 0; e < E_NUM; ++e) { lg[e] = acc[e] + br[e]; mx = fmaxf(mx, lg[e]); }
            float sum = 0.f;
#pragma unroll
            for (int e = 0; e < E_NUM; ++e) { g[e] = __expf(lg[e] - mx); sum += g[e]; }
            float inv = 1.f / sum;
#pragma unroll
            for (int e = 0; e < E_NUM; ++e) g[e] *= inv;
            int e1 = 0; float v1 = g[0];
#pragma unroll
            for (int e = 1; e < E_NUM; ++e) if (g[e] > v1) { v1 = g[e]; e1 = e; }
            int e2 = -1; float v2 = -1.f;
#pragma unroll
            for (int e = 0; e < E_NUM; ++e) if (e != e1 && g[e] > v2) { v2 = g[e]; e2 = e; }
            topk_idx[t * 2 + 0] = e1; topk_idx[t * 2 + 1] = e2;
            topk_w[t * 2 + 0] = v1;   topk_w[t * 2 + 1] = v2;
#pragma unroll
            for (int e = 0; e < E_NUM; ++e) atomicAdd(&blk_sg[e], g[e]);
            atomicAdd(&blk_cnt[e1], 1); atomicAdd(&blk_cnt[e2], 1);
        }
    }
    __syncthreads();
    if (threadIdx.x < E_NUM) {
        atomicAdd((float*)(meta + MI_SUMG) + threadIdx.x, blk_sg[threadIdx.x]);
        atomicAdd(meta + MI_COUNT + threadIdx.x, blk_cnt[threadIdx.x]);
    }
}

// =====================================================================
// fill_kernel (scan merged in): every block recomputes the 8-entry
// padded-offset prefix locally from MI_COUNT (stable after prep).
// Block 0 additionally writes MI_TOTAL / MI_RTE / aux_loss and zeroes
// the pad slots [off+cnt, off+padded) — disjoint from the cursor-
// allocated real-slot range, so no race with other blocks.
// =====================================================================
__global__ __launch_bounds__(256) void fill_kernel(
    const int* __restrict__ topk_idx, const float* __restrict__ topk_w,
    int* __restrict__ meta, int* __restrict__ slot_token, float* __restrict__ slot_weight,
    int* __restrict__ slot_of, float* __restrict__ out_aux)
{
    __shared__ int offs[E_NUM + 1];
    const int tid = threadIdx.x;
    if (tid <= E_NUM) {
        int off = 0;
        for (int e = 0; e < tid; ++e)
            off += ((meta[MI_COUNT + e] + 127) >> 7) << 7;
        offs[tid] = off;
    }
    __syncthreads();

    const int t = blockIdx.x * 256 + tid;
#pragma unroll
    for (int k = 0; k < 2; ++k) {
        int e = topk_idx[t * 2 + k];
        int p = atomicAdd(meta + MI_CURSOR + e, 1);
        int slot = offs[e] + p;
        slot_token[slot] = t;
        slot_weight[slot] = topk_w[t * 2 + k];
        slot_of[t * 2 + k] = slot;
    }

    if (blockIdx.x == 0) {
        const int total = offs[E_NUM] >> 7;
        // rowtile -> expert table
        for (int rt = tid; rt < total; rt += 256) {
            int row = rt << 7, e = 0;
#pragma unroll
            for (int k = 1; k < E_NUM; ++k) if (row >= offs[k]) e = k;
            meta[MI_RTE + rt] = e;
        }
        // pad slots: token 0 / weight 0
        for (int e = 0; e < E_NUM; ++e) {
            const int cnt = meta[MI_COUNT + e];
            const int hi = offs[e + 1];
            for (int i = offs[e] + cnt + tid; i < hi; i += 256) {
                slot_token[i] = 0;
                slot_weight[i] = 0.f;
            }
        }
        if (tid == 0) {
            meta[MI_TOTAL] = total;
            const float* sg = (const float*)(meta + MI_SUMG);
            float aux = 0.f;
            for (int e = 0; e < E_NUM; ++e)
                aux += (sg[e] / (float)N_TOK) * ((float)meta[MI_COUNT + e] / (float)N_TOK);
            out_aux[0] = aux * (float)E_NUM / (float)N_TOK;
        }
    }
}

// =====================================================================
// m97-proportion GEMM: 128x128 tile, BK=64, 256 threads (4 waves, 2x2
// grid of 64x64 wave tiles), SINGLE-buffered 32 KiB LDS (raw overlay).
// __launch_bounds__(256,4): VGPR budget 128 — acc=64 fits; (256,5)
// spilled (R11, 2.7x regression). Do not raise.
// SWZ: chunked XCD swizzle — ON for gemm2, OFF for gemm1.
// FUSET: blocks with blockIdx.y >= MAX_RT run the W2 transpose.
// =====================================================================

template<int KD, int NCOLS, int KSPLIT, bool GATHER, bool GELU, bool BIAS, bool SWZ, bool FUSET>
__global__ __launch_bounds__(256, 4) void gemm128_kernel(
    const f16* __restrict__ A, const f16* __restrict__ Bw,
    const float* __restrict__ bias, const int* __restrict__ slot_token,
    const int* __restrict__ meta, f16* __restrict__ Out, size_t out_kp_stride,
    const float* __restrict__ Tsrc, f16* __restrict__ Tdst)
{
    constexpr int KLOC = KD / KSPLIT;
    constexpr int NT = KLOC / 64;
    __shared__ __align__(16) char smem_raw[32768];
    f16* As = (f16*)smem_raw;             // 16 KiB
    f16* Bs = (f16*)(smem_raw + 16384);   // 16 KiB

    if (FUSET && blockIdx.y >= MAX_RT) {
        // ---- fused W2 transpose tail: R=DF, C=D, 8192 blocks ----
        const int id = (blockIdx.y - MAX_RT) * gridDim.x + blockIdx.x;
        const int cx = id & 15, ry = (id >> 4) & 63, ez = id >> 10;
        transpose_tile(Tsrc + (size_t)ez * D_DIM * DF_DIM,
                       Tdst + (size_t)ez * D_DIM * DF_DIM,
                       DF_DIM, D_DIM, ry * 64, cx * 64, (float*)smem_raw);
        return;
    }

    int nt, rt, kp;
    if (SWZ) {
        const int gx = gridDim.x, gy = gridDim.y;
        const int nwg = gx * gy * gridDim.z;
        const int flat = (blockIdx.z * gy + blockIdx.y) * gx + blockIdx.x;
        const int swz = (flat & 7) * (nwg >> 3) + (flat >> 3);
        nt = swz % gx;
        const int tmp = swz / gx;
        rt = tmp % gy;
        kp = tmp / gy;
    } else {
        nt = blockIdx.x; rt = blockIdx.y; kp = blockIdx.z;
    }

    if (rt >= meta[MI_TOTAL]) return;
    const int e  = meta[MI_RTE + rt];
    const int kbase = kp * KLOC;

    const int tid = threadIdx.x;
    const int w = tid >> 6, l = tid & 63;
    const int wr2 = w >> 1, wc2 = w & 1;        // 2 (M) x 2 (N) waves, 64x64 each
    const int fr = l & 15, fq = l >> 4;

    const int srow = tid >> 3;                  // 0..31
    const int kcs  = (tid & 7) ^ (srow & 7);    // pre-swizzled source chunk

    const f16* asrc[4]; const f16* bsrc[4];
#pragma unroll
    for (int i = 0; i < 4; ++i) {
        int r = i * 32 + srow;                  // row within 128-tile
        int ar;
        if (GATHER) ar = slot_token[rt * 128 + r];
        else        ar = rt * 128 + r;
        asrc[i] = A + (size_t)ar * KD + kbase + kcs * 8;
        bsrc[i] = Bw + ((size_t)e * NCOLS + (size_t)nt * 128 + r) * KD + kbase + kcs * 8;
    }

    const int rA  = wr2 * 64 + fr;
    const int rB  = wc2 * 64 + fr;
    const int sw0 = ( fq      ^ (fr & 7)) * 8;  // swizzled chunk offsets (f16 units), kk=0
    const int sw1 = ((4 + fq) ^ (fr & 7)) * 8;  // kk=32

    floatx4 acc[4][4];
#pragma unroll
    for (int m = 0; m < 4; ++m)
#pragma unroll
        for (int n = 0; n < 4; ++n) acc[m][n] = (floatx4){0.f, 0.f, 0.f, 0.f};

    half8 af[4], bf[4];

#pragma unroll 2
    for (int t = 0; t < NT; ++t) {
        // stage tile t (single buffer)
#pragma unroll
        for (int i = 0; i < 4; ++i) {
            gld_lds16(asrc[i] + (size_t)t * 64, &As[i * 2048 + tid * 8]);
            gld_lds16(bsrc[i] + (size_t)t * 64, &Bs[i * 2048 + tid * 8]);
        }
        asm volatile("s_waitcnt vmcnt(0)" ::: "memory");
        __builtin_amdgcn_s_barrier();
        // compute: 2 kk-halves x (8 ds_read + 16 MFMA)
#pragma unroll
        for (int kk2 = 0; kk2 < 2; ++kk2) {
            const int sw = kk2 ? sw1 : sw0;
#pragma unroll
            for (int mj = 0; mj < 4; ++mj)
                af[mj] = *(const half8*)&As[(size_t)(rA + mj * 16) * 64 + sw];
#pragma unroll
            for (int nj = 0; nj < 4; ++nj)
                bf[nj] = *(const half8*)&Bs[(size_t)(rB + nj * 16) * 64 + sw];
#pragma unroll
            for (int mj = 0; mj < 4; ++mj)
#pragma unroll
                for (int nj = 0; nj < 4; ++nj)
                    acc[mj][nj] = __builtin_amdgcn_mfma_f32_16x16x32_f16(
                        af[mj], bf[nj], acc[mj][nj], 0, 0, 0);
        }
        __builtin_amdgcn_s_barrier();   // all reads consumed before next stage
    }

    // ---- epilogue: 64 outputs/thread ----
    f16* Op = Out + (size_t)kp * out_kp_stride;
    const int orow0 = rt * 128 + wr2 * 64;
    const int ocol0 = nt * 128 + wc2 * 64;
#pragma unroll
    for (int mj = 0; mj < 4; ++mj) {
#pragma unroll
        for (int nj = 0; nj < 4; ++nj) {
            const int col = ocol0 + nj * 16 + fr;
            float bs = 0.f;
            if (BIAS) bs = bias[(size_t)e * NCOLS + col];
#pragma unroll
            for (int j = 0; j < 4; ++j) {
                const int row = orow0 + mj * 16 + fq * 4 + j;
                float v = acc[mj][nj][j] + bs;
                if (GELU) v = gelu_f(v);
                Op[(size_t)row * NCOLS + col] = (f16)v;
            }
        }
    }
}

// ------- combine: out[t] = w0*(P0[s0]+P1[s0]+b2[e0]) + w1*(P0[s1]+P1[s1]+b2[e1]) -------
__global__ __launch_bounds__(256) void combine_kernel(
    const f16* __restrict__ P, const int* __restrict__ slot_of,
    const int* __restrict__ topk_idx, const float* __restrict__ topk_w,
    const float* __restrict__ b2, float* __restrict__ out)
{
    const int t = blockIdx.x;
    const int c = threadIdx.x;          // 256 threads x 4 cols
    const size_t PS = (size_t)MAX_SLOTS * D_DIM;
    const int s0 = slot_of[t * 2], s1 = slot_of[t * 2 + 1];
    const int e0 = topk_idx[t * 2], e1 = topk_idx[t * 2 + 1];
    const float w0 = topk_w[t * 2], w1 = topk_w[t * 2 + 1];
    half4 a0 = *(const half4*)(P + (size_t)s0 * D_DIM + c * 4);
    half4 a1 = *(const half4*)(P + PS + (size_t)s0 * D_DIM + c * 4);
    half4 c0 = *(const half4*)(P + (size_t)s1 * D_DIM + c * 4);
    half4 c1 = *(const half4*)(P + PS + (size_t)s1 * D_DIM + c * 4);
    float4 bb0 = *(const float4*)(b2 + (size_t)e0 * D_DIM + c * 4);
    float4 bb1 = *(const float4*)(b2 + (size_t)e1 * D_DIM + c * 4);
    float4 o;
    o.x = w0 * ((float)a0[0] + (float)a1[0] + bb0.x) + w1 * ((float)c0[0] + (float)c1[0] + bb1.x);
    o.y = w0 * ((float)a0[1] + (float)a1[1] + bb0.y) + w1 * ((float)c0[1] + (float)c1[1] + bb1.y);
    o.z = w0 * ((float)a0[2] + (float)a1[2] + bb0.z) + w1 * ((float)c0[2] + (float)c1[2] + bb1.z);
    o.w = w0 * ((float)a0[3] + (float)a1[3] + bb0.w) + w1 * ((float)c0[3] + (float)c1[3] + bb1.w);
    *(float4*)(out + (size_t)t * D_DIM + c * 4) = o;
}

extern "C" void kernel_launch(void* const* d_in, const int* in_sizes, int n_in,
                              void* d_out, int out_size, void* d_ws, size_t ws_size,
                              hipStream_t stream) {
    const float* x  = (const float*)d_in[0];
    const float* Wr = (const float*)d_in[1];
    const float* br = (const float*)d_in[2];
    const float* W1 = (const float*)d_in[3];
    const float* b1 = (const float*)d_in[4];
    const float* W2 = (const float*)d_in[5];
    const float* b2 = (const float*)d_in[6];
    float* out = (float*)d_out;

    char* ws = (char*)d_ws;
    const size_t SZ_XH  = (size_t)N_TOK * D_DIM * 2;          // 16 MiB
    const size_t SZ_W1T = (size_t)E_NUM * DF_DIM * D_DIM * 2; // 64 MiB
    const size_t SZ_W2T = SZ_W1T;
    const size_t SZ_H   = (size_t)MAX_SLOTS * DF_DIM * 2;     // 136 MiB

    f16* xh  = (f16*)(ws);
    f16* W1t = (f16*)(ws + SZ_XH);
    f16* W2t = (f16*)(ws + SZ_XH + SZ_W1T);
    f16* H   = (f16*)(ws + SZ_XH + SZ_W1T + SZ_W2T);
    // P (2 split-K partials, 34 MiB each) aliases [xh | W1t] (80 MiB) — dead after gemm1.
    f16* P   = (f16*)ws;
    char* p  = ws + SZ_XH + SZ_W1T + SZ_W2T + SZ_H;
    int*   topk_idx    = (int*)p;    p += (size_t)N_TOK * 2 * 4;
    float* topk_w      = (float*)p;  p += (size_t)N_TOK * 2 * 4;
    int*   slot_token  = (int*)p;    p += (size_t)MAX_SLOTS * 4;
    float* slot_weight = (float*)p;  p += (size_t)MAX_SLOTS * 4;
    int*   slot_of     = (int*)p;    p += (size_t)N_TOK * 2 * 4;
    int*   meta        = (int*)p;

    // per-call init: zero meta only (counts/cursors/sumg). Slot arrays are
    // fully written by fill (real slots via cursors, pad slots by block 0).
    hipMemsetAsync(meta, 0, 1024, stream);

    // prep: W1 transpose + router (8704 blocks). W2 transpose rides in gemm1.
    prep_kernel<<<8704, 256, 0, stream>>>(
        W1, W1t, x, Wr, br, topk_idx, topk_w, meta, xh);

    // fill (scan merged): slots, pads, RTE table, total, aux loss
    fill_kernel<<<N_TOK / 256, 256, 0, stream>>>(
        topk_idx, topk_w, meta, slot_token, slot_weight, slot_of,
        out + (size_t)N_TOK * D_DIM);

    // GEMM1 + fused W2 transpose tail: H = gelu(gather(xh) @ W1t + b1)
    gemm128_kernel<D_DIM, DF_DIM, 1, true, true, true, false, true>
        <<<dim3(DF_DIM / 128, MAX_RT + 256, 1), 256, 0, stream>>>(
        xh, W1t, b1, slot_token, meta, H, 0, W2, W2t);

    // GEMM2 (XCD swizzle, split-K=2): P[kp] = H @ W2t
    gemm128_kernel<DF_DIM, D_DIM, 2, false, false, false, true, false>
        <<<dim3(D_DIM / 128, MAX_RT, 2), 256, 0, stream>>>(
        H, W2t, nullptr, slot_token, meta, P, (size_t)MAX_SLOTS * D_DIM, nullptr, nullptr);

    combine_kernel<<<N_TOK, 256, 0, stream>>>(P, slot_of, topk_idx, topk_w, b2, out);

    (void)in_sizes; (void)n_in; (void)ws_size;
}